// Round 10
// baseline (457.029 us; speedup 1.0000x reference)
//
#include <hip/hip_runtime.h>
#include <math.h>

#define Bq 2
#define NEG 16
#define Nn 10000
#define Ee 80000
#define Dd 128
#define NUM_REL 237
#define Ll 3
#define K_SEL 1000
#define BN (Bq*Nn)
#define EPSV 1e-5f
#define MAXACT 2048
#define MAXTOUCH 8192
#define SELCAP 3328
#define LN2F 0.69314718056f

// ---------------- workspace layout (bytes) ----------------
constexpr size_t HID_OFF   = 0;                                   // BN*D f32
constexpr size_t SCORE_OFF = HID_OFF   + (size_t)BN*Dd*4;         // BN f32
constexpr size_t CVEC_OFF  = SCORE_OFF + (size_t)BN*4;            // B*D f32
constexpr size_t HDR_OFF   = CVEC_OFF  + (size_t)Bq*Dd*4;         // 64 i32
constexpr size_t THR_OFF   = HDR_OFF   + 64*4;                    // B u64
constexpr size_t INC_OFF   = THR_OFF   + Bq*8;                    // BN u32 (per-node selected-in-edge count)
constexpr size_t DEG_OFF   = INC_OFF   + (size_t)BN*4;            // Nn u32 (static out-degree, computed once)
constexpr size_t SLOT_OFF  = DEG_OFF   + (size_t)BN*4;            // BN i32
constexpr size_t CNT_OFF   = SLOT_OFF  + (size_t)BN*4;            // MAXACT u32 (unused; layout kept)
constexpr size_t SDEG_OFF  = CNT_OFF   + (size_t)MAXACT*4;        // MAXACT f32
constexpr size_t S1_OFF    = SDEG_OFF  + (size_t)MAXACT*4;        // MAXACT*D f32
constexpr size_t S2_OFF    = S1_OFF    + (size_t)MAXACT*Dd*4;
constexpr size_t MXB_OFF   = S2_OFF    + (size_t)MAXACT*Dd*4;     // MAXACT*D u32
constexpr size_t MNB_OFF   = MXB_OFF   + (size_t)MAXACT*Dd*4;
constexpr size_t TPART_OFF = MNB_OFF   + (size_t)MAXACT*Dd*4;     // 4*MAXACT*D f32
constexpr size_t ALIST_OFF = TPART_OFF + (size_t)4*MAXACT*Dd*4;   // MAXACT i32
constexpr size_t FLAG_OFF  = ALIST_OFF + (size_t)MAXACT*4;        // BN u32
constexpr size_t TLIST_OFF = FLAG_OFF  + (size_t)BN*4;            // MAXTOUCH i32
constexpr size_t EDGE_OFF  = TLIST_OFF + (size_t)MAXTOUCH*4;      // B*E*2 i32
constexpr size_t CTR_OFF   = EDGE_OFF  + (size_t)Bq*Ee*2*4;       // 16 u32
// ctr[0]=na ctr[1]=ne ctr[2]=sum(log(deg+1)) f32-bits ctr[3]=ntouched ctr[4]=sc0 f32-bits

// ---------------- helpers ----------------
__device__ __forceinline__ unsigned encf(float f){
  unsigned u = __float_as_uint(f);
  return (u & 0x80000000u) ? ~u : (u | 0x80000000u);
}
__device__ __forceinline__ float decf(unsigned e){
  unsigned u = (e & 0x80000000u) ? (e & 0x7FFFFFFFu) : ~e;
  return __uint_as_float(u);
}
__device__ __forceinline__ unsigned long long make_key(float f, int i){
  unsigned d = ~encf(f);
  return ((unsigned long long)d << 32) | (unsigned)i;
}

// ---------------- k_init: prep (block 0) || zero hidden/flag/deg0 + score fill (blocks >= 1) ----------------
__global__ __launch_bounds__(256) void k_init(
    const int* __restrict__ h_index, const int* __restrict__ r_index, const int* __restrict__ t_index,
    const float* __restrict__ hidden_states, const float* __restrict__ rel_embedding,
    const float* __restrict__ lin_W, const float* __restrict__ lin_b,
    const float* __restrict__ m1_W, const float* __restrict__ m1_b,
    const float* __restrict__ m2_W, const float* __restrict__ m2_b,
    int* __restrict__ hdr, float* __restrict__ cvec, float* __restrict__ hidden,
    float* __restrict__ score, unsigned* __restrict__ flag, int* __restrict__ tlist,
    unsigned* __restrict__ deg0, unsigned* __restrict__ ctr)
{
  __shared__ struct {
    int hbuf[Bq*NEG], tbuf[Bq*NEG], rbuf[Bq*NEG];
    int fh[Bq], ft[Bq], r0[Bq], eqf[Bq], hsrc, tsrc;
    float s0red[Dd]; float sc0;
    float relv[Bq][Dd], cv[Bq][Dd], hv[Dd], x[Bq][Dd], p[Bq][Dd];
  } sp;
  const int tid = threadIdx.x;
  const int bid = blockIdx.x;
  if (tid < Bq*NEG){
    sp.hbuf[tid] = h_index[tid];
    sp.tbuf[tid] = t_index[tid];
    sp.rbuf[tid] = r_index[tid];
  }
  if (tid < Dd) sp.s0red[tid] = fmaxf(m1_b[tid], 0.f) * m2_W[tid];
  __syncthreads();
  if (tid == 0){
    for (int b = 0; b < Bq; b++){
      bool eq = true;
      for (int j = 1; j < NEG; j++) eq = eq && (sp.hbuf[b*NEG+j] == sp.hbuf[b*NEG]);
      int h0 = eq ? sp.hbuf[b*NEG] : sp.tbuf[b*NEG];
      int t0 = eq ? sp.tbuf[b*NEG] : sp.hbuf[b*NEG];
      int r0 = eq ? sp.rbuf[b*NEG] : sp.rbuf[b*NEG] + NUM_REL;
      sp.fh[b] = h0 + b*Nn; sp.ft[b] = t0 + b*Nn;
      sp.r0[b] = r0; sp.eqf[b] = eq ? 1 : 0;
      if (b == 0){ sp.hsrc = h0; sp.tsrc = t0; }
    }
    float s = m2_b[0];
    for (int k = 0; k < Dd; k++) s += sp.s0red[k];
    sp.sc0 = s;
    if (bid == 0){
      ctr[4] = __float_as_uint(s);
      hdr[0] = sp.fh[0]; hdr[1] = sp.fh[1];
      hdr[2] = sp.ft[0]; hdr[3] = sp.ft[1];
      for (int b = 0; b < Bq; b++)
        for (int j = 0; j < NEG; j++){
          int tj = sp.eqf[b] ? sp.tbuf[b*NEG+j] : sp.hbuf[b*NEG+j];
          hdr[4 + b*NEG + j] = tj + b*Nn;
        }
      int cand[4] = { sp.ft[0], sp.fh[0], sp.ft[1], sp.fh[1] };
      int n = 0;
      for (int c = 0; c < 4; c++){
        bool dup = false;
        for (int m = 0; m < n; m++) dup = dup || (tlist[m] == cand[c]);
        if (!dup) tlist[n++] = cand[c];
        flag[cand[c]] = 1u;
      }
      ctr[3] = (unsigned)n;
    }
  }
  __syncthreads();
  const int fh0 = sp.fh[0], fh1 = sp.fh[1];
  const int ft0 = sp.ft[0], ft1 = sp.ft[1];
  const float sc0 = sp.sc0;
  if (bid == 0){
    int b = tid >> 7, d = tid & 127;
    sp.relv[b][d] = rel_embedding[(size_t)sp.r0[b]*Dd + d];
    if (b == 0) sp.hv[d] = hidden_states[(size_t)sp.hsrc*Dd + d];
    __syncthreads();
    float acc = lin_b[d];
    #pragma unroll 8
    for (int k = 0; k < Dd; k++) acc += sp.relv[b][k]*lin_W[(Dd+k)*Dd + d];
    sp.cv[b][d] = acc; cvec[b*Dd + d] = acc;
    // boundary scatter: t first, h second (h overrides; same thread => ordered)
    hidden[(size_t)sp.ft[b]*Dd + d] = hidden_states[(size_t)sp.tsrc*Dd + d];
    hidden[(size_t)sp.fh[b]*Dd + d] = hidden_states[(size_t)sp.hsrc*Dd + d];
    __syncthreads();
    float hv = sp.hv[d];
    float heur = sp.cv[b][d];
    #pragma unroll 8
    for (int k = 0; k < Dd; k++) heur += sp.hv[k]*lin_W[k*Dd + d];
    sp.x[b][d] = heur * hv;
    __syncthreads();
    float a2 = m1_b[d];
    #pragma unroll 8
    for (int k = 0; k < Dd; k++) a2 += sp.x[b][k]*m1_W[k*Dd + d];
    sp.p[b][d] = fmaxf(a2, 0.f) * m2_W[d];
    __syncthreads();
    if (tid < Bq){
      float s = m2_b[0];
      for (int k = 0; k < Dd; k++) s += sp.p[tid][k];
      score[sp.fh[tid]] = s;
    }
  } else {
    int zb = bid - 1, znb = gridDim.x - 1;
    int zt = zb*256 + tid, zs = znb*256;
    float4 z4 = make_float4(0.f, 0.f, 0.f, 0.f);
    for (int i = zt; i < BN*32; i += zs){
      int row = i >> 5;
      if (row != ft0 && row != ft1 && row != fh0 && row != fh1)
        ((float4*)hidden)[i] = z4;
    }
    for (int v = zt; v < BN; v += zs){
      if (v != ft0 && v != ft1 && v != fh0 && v != fh1) flag[v] = 0u;
      if (v != fh0 && v != fh1) score[v] = sc0;
      if (v < Nn) deg0[v] = 0u;
    }
  }
}

// ---------------- k_selzero: radix top-K (blocks 0..Bq-1) || per-layer zeroing (blocks >= Bq)
// do_deg0 (layer 0 only): zero-blocks also accumulate the static out-degree histogram.
__global__ __launch_bounds__(256) void k_selzero(
    const float* __restrict__ score, const int* __restrict__ tlist,
    unsigned long long* __restrict__ thr,
    float* __restrict__ s1, float* __restrict__ s2,
    unsigned* __restrict__ mxb, unsigned* __restrict__ mnb,
    unsigned* __restrict__ incnt, unsigned* __restrict__ ctr,
    const int* __restrict__ ei, unsigned* __restrict__ deg0, int do_deg0)
{
  int tid = threadIdx.x;
  int bid = blockIdx.x;
  if (bid < Bq){
    int b = bid;
    int nt = (int)ctr[3];
    unsigned d0 = ~encf(__uint_as_float(ctr[4]));
    __shared__ unsigned sd[SELCAP];
    __shared__ unsigned short sidx[SELCAP];
    __shared__ unsigned hist[256], histT[256];
    __shared__ int ntb_sh;
    __shared__ unsigned long long pref_sh;
    __shared__ unsigned kk_sh;
    if (tid == 0){ ntb_sh = 0; pref_sh = 0ull; kk_sh = K_SEL; }
    __syncthreads();
    int vlo = b*Nn, vhi = vlo + Nn;
    for (int i = tid; i < nt; i += 256){
      int v = tlist[i];
      if (v >= vlo && v < vhi){
        int pos = atomicAdd(&ntb_sh, 1);
        if (pos < SELCAP){
          sd[pos] = ~encf(score[v]);
          sidx[pos] = (unsigned short)(v - vlo);
        }
      }
    }
    __syncthreads();
    int ntb = min(ntb_sh, SELCAP);
    unsigned nvirt = (unsigned)(Nn - ntb);
    for (int pass = 7; pass >= 0; --pass){
      hist[tid] = 0u; histT[tid] = 0u;
      __syncthreads();
      unsigned long long pref = pref_sh;
      int sh_hi = 8*(pass+1);
      for (int j = tid; j < ntb; j += 256){
        unsigned long long key = ((unsigned long long)sd[j] << 32) | (unsigned long long)sidx[j];
        bool ok = (pass==7) || ((key >> sh_hi) == (pref >> sh_hi));
        if (ok) atomicAdd(&hist[(unsigned)(key >> (8*pass)) & 255u], 1u);
        if (pass < 4){
          unsigned idx = sidx[j];
          bool oki = (pass == 3) || ((idx >> sh_hi) == (((unsigned)pref) >> sh_hi));
          if (oki) atomicAdd(&histT[(idx >> (8*pass)) & 255u], 1u);
        }
      }
      __syncthreads();
      if (pass >= 4){
        if (tid == 0){
          unsigned long long keyv_hi = ((unsigned long long)d0 << 32);
          bool ok = (pass==7) || ((keyv_hi >> sh_hi) == (pref_sh >> sh_hi));
          if (ok) atomicAdd(&hist[(d0 >> (8*(pass-4))) & 255u], nvirt);
        }
      } else {
        if ((unsigned)(pref >> 32) == d0){
          unsigned long long hf = 0ull;
          if (pass < 3) hf = (unsigned long long)((((unsigned)pref) >> sh_hi)) << sh_hi;
          unsigned long long lo = hf + ((unsigned long long)tid << (8*pass));
          unsigned long long hi = lo + (1ull << (8*pass));
          unsigned long long nn = (unsigned long long)Nn;
          unsigned long long l2 = lo < nn ? lo : nn;
          unsigned long long h2 = hi < nn ? hi : nn;
          if (h2 > l2){
            unsigned c = (unsigned)(h2 - l2) - histT[tid];
            if (c > 0u) atomicAdd(&hist[tid], c);
          }
        }
      }
      __syncthreads();
      {
        unsigned kk = kk_sh;
        unsigned cum = 0;
        for (int i = 0; i < tid; i++) cum += hist[i];
        unsigned h = hist[tid];
        if (h > 0u && cum < kk && kk <= cum + h){
          pref_sh |= ((unsigned long long)tid) << (8*pass);
          kk_sh = kk - cum;
        }
      }
      __syncthreads();
    }
    if (tid == 0) thr[b] = pref_sh;
  } else {
    int zb = bid - Bq, znb = gridDim.x - Bq;
    int zt = zb*256 + tid, zs = znb*256;
    for (int i = zt; i < MAXACT*Dd; i += zs){
      s1[i] = 0.f; s2[i] = 0.f; mxb[i] = 0u; mnb[i] = 0xFFFFFFFFu;
    }
    for (int i = zt; i < BN; i += zs) incnt[i] = 0u;
    if (zt < 3) ctr[zt] = 0u;
    if (do_deg0){
      for (int e = zt; e < Ee; e += zs) atomicAdd(&deg0[ei[e]], 1u);
    }
  }
}

// ---------------- k_build: active-node + edge compaction, wave-aggregated counters ----------------
__global__ void k_build(const int* __restrict__ ei, const float* __restrict__ score,
                        const unsigned long long* __restrict__ thr,
                        const unsigned* __restrict__ deg0,
                        int* __restrict__ node_slot, int* __restrict__ alist,
                        float* __restrict__ slot_deg, unsigned* __restrict__ incnt,
                        int* __restrict__ edges, unsigned* __restrict__ ctr,
                        unsigned* __restrict__ flag, int* __restrict__ tlist){
  int i = blockIdx.x*blockDim.x + threadIdx.x;
  int lane = threadIdx.x & 63;
  unsigned long long lmask = (1ull << lane) - 1ull;
  unsigned long long th0 = thr[0], th1 = thr[1];
  __shared__ float blog;
  if (threadIdx.x == 0) blog = 0.f;
  __syncthreads();
  // ---- node part (i < BN) ----
  {
    bool pn = false; unsigned dg = 0;
    int b = (i >= Nn) ? 1 : 0;
    int v0 = i - b*Nn;
    if (i < BN){
      dg = deg0[v0];
      pn = (dg > 0u) && (make_key(score[i], v0) <= (b ? th1 : th0));
    }
    unsigned long long mn_ = __ballot(pn);
    if (mn_ != 0ull){
      int lead = __ffsll((unsigned long long)mn_) - 1;
      int base = 0;
      if (lane == lead) base = (int)atomicAdd(&ctr[0], (unsigned)__popcll(mn_));
      base = __shfl(base, lead);
      if (pn){
        int slot = base + __popcll(mn_ & lmask);
        alist[slot] = i; node_slot[i] = slot; slot_deg[slot] = (float)dg;
        atomicAdd(&blog, logf((float)dg + 1.0f));
      }
    }
    bool newt = false;
    if (pn) newt = (atomicExch(&flag[i], 1u) == 0u);
    unsigned long long mt = __ballot(newt);
    if (mt != 0ull){
      int lead = __ffsll((unsigned long long)mt) - 1;
      int base = 0;
      if (lane == lead) base = (int)atomicAdd(&ctr[3], (unsigned)__popcll(mt));
      base = __shfl(base, lead);
      if (newt) tlist[base + __popcll(mt & lmask)] = i;
    }
  }
  // ---- edge part (i < Ee) ----
  {
    bool pe0 = false, pe1 = false; int s0 = 0, d0e = 0;
    if (i < Ee){
      s0 = ei[i]; d0e = ei[Ee + i];
      unsigned dgd = deg0[d0e];
      if (dgd > 0u){
        pe0 = (make_key(score[s0], s0) <= th0) && (make_key(score[d0e], d0e) <= th0);
        pe1 = (make_key(score[s0 + Nn], s0) <= th1) && (make_key(score[d0e + Nn], d0e) <= th1);
      }
    }
    unsigned long long m0 = __ballot(pe0);
    if (m0 != 0ull){
      int lead = __ffsll((unsigned long long)m0) - 1;
      int base = 0;
      if (lane == lead) base = (int)atomicAdd(&ctr[1], (unsigned)__popcll(m0));
      base = __shfl(base, lead);
      if (pe0){
        int j = base + __popcll(m0 & lmask);
        edges[2*j] = s0; edges[2*j+1] = d0e;
        atomicAdd(&incnt[d0e], 1u);
      }
    }
    unsigned long long m1 = __ballot(pe1);
    if (m1 != 0ull){
      int lead = __ffsll((unsigned long long)m1) - 1;
      int base = 0;
      if (lane == lead) base = (int)atomicAdd(&ctr[1], (unsigned)__popcll(m1));
      base = __shfl(base, lead);
      if (pe1){
        int j = base + __popcll(m1 & lmask);
        edges[2*j] = s0 + Nn; edges[2*j+1] = d0e + Nn;
        atomicAdd(&incnt[d0e + Nn], 1u);
      }
    }
  }
  __syncthreads();
  if (threadIdx.x == 0 && blog != 0.f) atomicAdd((float*)&ctr[2], blog);
}

// ---------------- k_messages: pre GEMV per edge, 8 edges/block, atomic aggregation ----------------
__global__ __launch_bounds__(256) void k_messages(
    const float* __restrict__ hidden, const int* __restrict__ edges,
    const int* __restrict__ node_slot,
    const float* __restrict__ preW, const float* __restrict__ preb,
    float* __restrict__ s1, float* __restrict__ s2,
    unsigned* __restrict__ mxb, unsigned* __restrict__ mnb,
    const unsigned* __restrict__ ctr){
  int ne = (int)ctr[1];
  int tid = threadIdx.x;
  int half = tid >> 7, d = tid & 127;
  __shared__ float sd[8][Dd], ss[8][Dd];
  float pb = preb[d];
  for (int j0 = blockIdx.x*8; j0 < ne; j0 += gridDim.x*8){
    int base = j0 + half*4;
    int nv = ne - base; if (nv > 4) nv = 4; if (nv < 0) nv = 0;
    int dsl[4];
    #pragma unroll
    for (int e = 0; e < 4; e++){
      int j = (e < nv) ? base + e : j0;      // dummy edges read j0 (valid), write nothing
      int s = edges[2*j]; int dv = edges[2*j+1];
      dsl[e] = node_slot[dv];
      sd[half*4+e][d] = hidden[(size_t)dv*Dd + d];
      ss[half*4+e][d] = hidden[(size_t)s*Dd + d];
    }
    __syncthreads();
    float a[4] = {pb, pb, pb, pb};
    #pragma unroll 4
    for (int k = 0; k < Dd; k++){
      float w0 = preW[k*Dd + d];
      float w1 = preW[(Dd+k)*Dd + d];
      #pragma unroll
      for (int e = 0; e < 4; e++)
        a[e] += sd[half*4+e][k]*w0 + ss[half*4+e][k]*w1;
    }
    for (int e = 0; e < nv; e++){
      int dslot = dsl[e];
      atomicAdd(&s1[dslot*Dd + d], a[e]);
      atomicAdd(&s2[dslot*Dd + d], a[e]*a[e]);
      atomicMax(&mxb[dslot*Dd + d], encf(a[e]));
      atomicMin(&mnb[dslot*Dd + d], encf(a[e]));
    }
    __syncthreads();
  }
}

// ---------------- k_post: finalize aggregators + post GEMM (tpart) ----------------
__global__ __launch_bounds__(512) void k_post(
    const unsigned* __restrict__ incnt, const int* __restrict__ alist,
    const float* __restrict__ s1, const float* __restrict__ s2,
    const unsigned* __restrict__ mxb, const unsigned* __restrict__ mnb,
    const float* __restrict__ slot_deg,
    const float* __restrict__ postW, float* __restrict__ tpart,
    const unsigned* __restrict__ ctr){
  int na = (int)ctr[0];
  int bid = blockIdx.x;
  int tile = bid & 63, ch = bid >> 6;
  if (tile*32 >= na) return;
  float logsum = __uint_as_float(ctr[2]);
  float avg = (logsum + (float)(BN - na)*LN2F) / (float)BN;
  __shared__ float lb[32*136];
  __shared__ float wbuf[3*16*128];
  __shared__ float sden[32];
  __shared__ unsigned shas[32];
  int tid = threadIdx.x;
  if (tid < 32){
    int slot = tile*32 + tid;
    unsigned c = (slot < na) ? incnt[alist[slot]] : 0u;
    sden[tid] = fmaxf((float)c, 1.0f);
    shas[tid] = c;
  }
  __syncthreads();
  for (int idx = tid; idx < 32*Dd; idx += 512){
    int sl = idx >> 7, kk = idx & 127;
    int gi = (tile*32 + sl)*Dd + kk;
    float den = sden[sl];
    float val;
    if (ch == 0)      val = s1[gi]/den;
    else if (ch == 1) val = shas[sl] ? decf(mxb[gi]) : 0.f;
    else if (ch == 2) val = shas[sl] ? decf(mnb[gi]) : 0.f;
    else {
      float mv = s1[gi]/den;
      float var = s2[gi]/den - mv*mv;
      val = sqrtf(fmaxf(var, 0.f) + EPSV);
    }
    lb[sl*136 + kk] = val;
  }
  int cg = tid & 31, rg = tid >> 5;        // 32 col-groups x 16 row-groups (2 rows)
  int c0 = cg*4;
  float a0[2][4], a1[2][4], a2[2][4];
  #pragma unroll
  for (int i = 0; i < 2; i++)
    #pragma unroll
    for (int j = 0; j < 4; j++){ a0[i][j]=0.f; a1[i][j]=0.f; a2[i][j]=0.f; }
  for (int chunk = 0; chunk < 8; ++chunk){
    #pragma unroll
    for (int i = 0; i < 3; ++i){
      int f = tid + i*512;                 // 1536 float4
      int q = f >> 9, r = f & 511;
      int kk = r >> 5, c4 = r & 31;
      int grow = q*512 + ch*128 + chunk*16 + kk;
      ((float4*)wbuf)[f] = *(const float4*)(postW + (size_t)grow*Dd + c4*4);
    }
    __syncthreads();
    #pragma unroll
    for (int k4 = 0; k4 < 4; ++k4){
      float4 av0 = *(const float4*)&lb[(rg*2+0)*136 + chunk*16 + k4*4];
      float4 av1 = *(const float4*)&lb[(rg*2+1)*136 + chunk*16 + k4*4];
      #pragma unroll
      for (int j = 0; j < 4; ++j){
        int kk = k4*4 + j;
        float4 w0 = *(const float4*)&wbuf[kk*128 + c0];
        float4 w1 = *(const float4*)&wbuf[(16+kk)*128 + c0];
        float4 w2 = *(const float4*)&wbuf[(32+kk)*128 + c0];
        float av[2] = { (&av0.x)[j], (&av1.x)[j] };
        #pragma unroll
        for (int i = 0; i < 2; i++){
          float a = av[i];
          a0[i][0] += a*w0.x; a0[i][1] += a*w0.y; a0[i][2] += a*w0.z; a0[i][3] += a*w0.w;
          a1[i][0] += a*w1.x; a1[i][1] += a*w1.y; a1[i][2] += a*w1.z; a1[i][3] += a*w1.w;
          a2[i][0] += a*w2.x; a2[i][1] += a*w2.y; a2[i][2] += a*w2.z; a2[i][3] += a*w2.w;
        }
      }
    }
    __syncthreads();
  }
  #pragma unroll
  for (int i = 0; i < 2; i++){
    int slot = tile*32 + rg*2 + i;
    if (slot < na){
      float dg = slot_deg[slot];
      float logd = logf(dg + 1.f);
      float al = logd/avg, be = avg/logd;
      float4 r;
      r.x = a0[i][0] + al*a1[i][0] + be*a2[i][0];
      r.y = a0[i][1] + al*a1[i][1] + be*a2[i][1];
      r.z = a0[i][2] + al*a1[i][2] + be*a2[i][2];
      r.w = a0[i][3] + al*a1[i][3] + be*a2[i][3];
      *(float4*)(tpart + (size_t)ch*MAXACT*Dd + (size_t)slot*Dd + c0) = r;
    }
  }
}

// ---------------- k_out_score: out GEMM + residual, then (do_score) rescore the updated rows ----------------
__global__ __launch_bounds__(256) void k_out_score(
    const float* __restrict__ tpart, const int* __restrict__ alist,
    const float* __restrict__ outW, const float* __restrict__ outb,
    const float* __restrict__ postb, float* __restrict__ hidden,
    const unsigned* __restrict__ ctr,
    const float* __restrict__ cvec, const float* __restrict__ linW,
    const float* __restrict__ m1W, const float* __restrict__ m1b,
    const float* __restrict__ m2W, const float* __restrict__ m2b,
    float* __restrict__ score, int do_score){
  int na = (int)ctr[0];
  int tile = blockIdx.x;
  if (tile*32 >= na) return;
  __shared__ union {
    struct { float tr[32*136]; float wbuf[16*128]; } p1;
    struct { float sh[32*Dd]; float sx[32*Dd]; float sc[2*Dd]; float red[32*33]; } p2;
  } sm;
  int tid = threadIdx.x;
  // ---- phase 1: out GEMM + residual (identical math to old k_out_resid) ----
  for (int idx = tid; idx < 32*Dd; idx += 256){
    int sl = idx >> 7, kk = idx & 127;
    size_t o = (size_t)(tile*32 + sl)*Dd + kk;
    sm.p1.tr[sl*136 + kk] = tpart[o] + tpart[(size_t)MAXACT*Dd + o]
                          + tpart[(size_t)2*MAXACT*Dd + o] + tpart[(size_t)3*MAXACT*Dd + o]
                          + postb[kk];
  }
  int cg = tid & 31, rg = tid >> 5;        // 32 col-groups x 8 row-groups (4 rows)
  int c0 = cg*4;
  float4 ob = *(const float4*)(outb + c0);
  float acc[4][4];
  #pragma unroll
  for (int r = 0; r < 4; r++){ acc[r][0]=ob.x; acc[r][1]=ob.y; acc[r][2]=ob.z; acc[r][3]=ob.w; }
  for (int chunk = 0; chunk < 8; ++chunk){
    #pragma unroll
    for (int i = 0; i < 2; ++i){
      int f = tid + i*256;                 // 512 float4
      int kk = f >> 5, c4 = f & 31;
      ((float4*)sm.p1.wbuf)[f] = *(const float4*)(outW + (size_t)(chunk*16 + kk)*Dd + c4*4);
    }
    __syncthreads();
    #pragma unroll
    for (int k4 = 0; k4 < 4; ++k4){
      float4 av[4];
      #pragma unroll
      for (int r = 0; r < 4; r++)
        av[r] = *(const float4*)&sm.p1.tr[(rg*4+r)*136 + chunk*16 + k4*4];
      #pragma unroll
      for (int j = 0; j < 4; ++j){
        float4 w = *(const float4*)&sm.p1.wbuf[(k4*4+j)*128 + c0];
        #pragma unroll
        for (int r = 0; r < 4; r++){
          float a = (&av[r].x)[j];
          acc[r][0] += a*w.x; acc[r][1] += a*w.y; acc[r][2] += a*w.z; acc[r][3] += a*w.w;
        }
      }
    }
    __syncthreads();
  }
  float4 h4s[4];
  #pragma unroll
  for (int r = 0; r < 4; r++){
    int slot = tile*32 + rg*4 + r;
    h4s[r] = make_float4(0.f, 0.f, 0.f, 0.f);
    if (slot < na){
      int v = alist[slot];
      float* hp = hidden + (size_t)v*Dd + c0;
      float4 h4 = *(float4*)hp;
      h4.x += acc[r][0]; h4.y += acc[r][1]; h4.z += acc[r][2]; h4.w += acc[r][3];
      *(float4*)hp = h4;
      h4s[r] = h4;
    }
  }
  if (!do_score) return;
  __syncthreads();                          // retire phase-1 LDS before union reuse
  // ---- phase 2: rescore these 32 rows (identical math to old k_score) ----
  sm.p2.sc[tid] = cvec[tid];
  #pragma unroll
  for (int r = 0; r < 4; r++)
    *(float4*)&sm.p2.sh[(rg*4+r)*Dd + c0] = h4s[r];
  __syncthreads();
  float ac2[4][4];
  #pragma unroll
  for (int i = 0; i < 4; i++){ ac2[i][0]=0.f; ac2[i][1]=0.f; ac2[i][2]=0.f; ac2[i][3]=0.f; }
  for (int k4 = 0; k4 < 32; k4++){
    float4 av[4];
    #pragma unroll
    for (int i = 0; i < 4; i++) av[i] = ((float4*)sm.p2.sh)[(rg*4+i)*32 + k4];
    #pragma unroll
    for (int j = 0; j < 4; j++){
      float4 w = *(const float4*)(linW + (size_t)(k4*4+j)*Dd + c0);
      #pragma unroll
      for (int i = 0; i < 4; i++){
        float a = (&av[i].x)[j];
        ac2[i][0] += a*w.x; ac2[i][1] += a*w.y; ac2[i][2] += a*w.z; ac2[i][3] += a*w.w;
      }
    }
  }
  #pragma unroll
  for (int i = 0; i < 4; i++){
    int row = rg*4 + i;
    int slot = tile*32 + row;
    int bb = (alist[slot] >= Nn) ? 1 : 0;   // slot < MAXACT always; stale reads for slot>=na unused
    float4 cv = *(float4*)&sm.p2.sc[bb*Dd + c0];
    float4 hv = ((float4*)sm.p2.sh)[row*32 + cg];
    float4 x;
    x.x = (ac2[i][0] + cv.x)*hv.x;
    x.y = (ac2[i][1] + cv.y)*hv.y;
    x.z = (ac2[i][2] + cv.z)*hv.z;
    x.w = (ac2[i][3] + cv.w)*hv.w;
    ((float4*)sm.p2.sx)[row*32 + cg] = x;
  }
  __syncthreads();
  #pragma unroll
  for (int i = 0; i < 4; i++){ ac2[i][0]=0.f; ac2[i][1]=0.f; ac2[i][2]=0.f; ac2[i][3]=0.f; }
  for (int k4 = 0; k4 < 32; k4++){
    float4 av[4];
    #pragma unroll
    for (int i = 0; i < 4; i++) av[i] = ((float4*)sm.p2.sx)[(rg*4+i)*32 + k4];
    #pragma unroll
    for (int j = 0; j < 4; j++){
      float4 w = *(const float4*)(m1W + (size_t)(k4*4+j)*Dd + c0);
      #pragma unroll
      for (int i = 0; i < 4; i++){
        float a = (&av[i].x)[j];
        ac2[i][0] += a*w.x; ac2[i][1] += a*w.y; ac2[i][2] += a*w.z; ac2[i][3] += a*w.w;
      }
    }
  }
  float4 mb = *(const float4*)(m1b + c0);
  float4 mw = *(const float4*)(m2W + c0);
  #pragma unroll
  for (int i = 0; i < 4; i++){
    float p0 = fmaxf(ac2[i][0]+mb.x, 0.f)*mw.x;
    float p1 = fmaxf(ac2[i][1]+mb.y, 0.f)*mw.y;
    float p2 = fmaxf(ac2[i][2]+mb.z, 0.f)*mw.z;
    float p3 = fmaxf(ac2[i][3]+mb.w, 0.f)*mw.w;
    sm.p2.red[(rg*4+i)*33 + cg] = p0+p1+p2+p3;
  }
  __syncthreads();
  if (tid < 32){
    int slot = tile*32 + tid;
    if (slot < na){
      float s = m2b[0];
      for (int g = 0; g < 32; g++) s += sm.p2.red[tid*33 + g];
      score[alist[slot]] = s;
    }
  }
}

// ---------------- k_score: score rows of `list`; to_score writes score[], else d_out ----------------
__global__ __launch_bounds__(256) void k_score(
    const float* __restrict__ hidden, const float* __restrict__ cvec,
    const float* __restrict__ linW,
    const float* __restrict__ m1W, const float* __restrict__ m1b,
    const float* __restrict__ m2W, const float* __restrict__ m2b,
    const int* __restrict__ list, int nt, float* __restrict__ outp,
    float* __restrict__ score_arr, int to_score){
  __shared__ float sh[32*Dd];
  __shared__ float sx[32*Dd];
  __shared__ float sc[2*Dd];
  __shared__ int   sv[32];
  __shared__ float red[32*33];
  int tid = threadIdx.x;
  if (tid < 32) sv[tid] = (tid < nt) ? list[tid] : list[0];
  sc[tid] = cvec[tid];
  __syncthreads();
  for (int q = tid; q < 32*32; q += 256){
    int row = q >> 5, f4 = q & 31;
    ((float4*)sh)[row*32 + f4] = ((const float4*)(hidden + (size_t)sv[row]*Dd))[f4];
  }
  __syncthreads();
  int cg = tid & 31, rg = tid >> 5;
  int c0 = cg*4;
  float acc[4][4];
  #pragma unroll
  for (int i = 0; i < 4; i++){ acc[i][0]=0.f; acc[i][1]=0.f; acc[i][2]=0.f; acc[i][3]=0.f; }
  for (int k4 = 0; k4 < 32; k4++){
    float4 av[4];
    #pragma unroll
    for (int i = 0; i < 4; i++) av[i] = ((float4*)sh)[(rg*4+i)*32 + k4];
    #pragma unroll
    for (int j = 0; j < 4; j++){
      float4 w = *(const float4*)(linW + (size_t)(k4*4+j)*Dd + c0);
      #pragma unroll
      for (int i = 0; i < 4; i++){
        float a = (&av[i].x)[j];
        acc[i][0] += a*w.x; acc[i][1] += a*w.y; acc[i][2] += a*w.z; acc[i][3] += a*w.w;
      }
    }
  }
  #pragma unroll
  for (int i = 0; i < 4; i++){
    int row = rg*4 + i;
    int bb = (sv[row] >= Nn) ? 1 : 0;
    float4 cv = *(float4*)&sc[bb*Dd + c0];
    float4 hv = ((float4*)sh)[row*32 + cg];
    float4 x;
    x.x = (acc[i][0] + cv.x)*hv.x;
    x.y = (acc[i][1] + cv.y)*hv.y;
    x.z = (acc[i][2] + cv.z)*hv.z;
    x.w = (acc[i][3] + cv.w)*hv.w;
    ((float4*)sx)[row*32 + cg] = x;
  }
  __syncthreads();
  #pragma unroll
  for (int i = 0; i < 4; i++){ acc[i][0]=0.f; acc[i][1]=0.f; acc[i][2]=0.f; acc[i][3]=0.f; }
  for (int k4 = 0; k4 < 32; k4++){
    float4 av[4];
    #pragma unroll
    for (int i = 0; i < 4; i++) av[i] = ((float4*)sx)[(rg*4+i)*32 + k4];
    #pragma unroll
    for (int j = 0; j < 4; j++){
      float4 w = *(const float4*)(m1W + (size_t)(k4*4+j)*Dd + c0);
      #pragma unroll
      for (int i = 0; i < 4; i++){
        float a = (&av[i].x)[j];
        acc[i][0] += a*w.x; acc[i][1] += a*w.y; acc[i][2] += a*w.z; acc[i][3] += a*w.w;
      }
    }
  }
  float4 mb = *(const float4*)(m1b + c0);
  float4 mw = *(const float4*)(m2W + c0);
  #pragma unroll
  for (int i = 0; i < 4; i++){
    float p0 = fmaxf(acc[i][0]+mb.x, 0.f)*mw.x;
    float p1 = fmaxf(acc[i][1]+mb.y, 0.f)*mw.y;
    float p2 = fmaxf(acc[i][2]+mb.z, 0.f)*mw.z;
    float p3 = fmaxf(acc[i][3]+mb.w, 0.f)*mw.w;
    red[(rg*4+i)*33 + cg] = p0+p1+p2+p3;
  }
  __syncthreads();
  if (tid < 32){
    float s = m2b[0];
    for (int g = 0; g < 32; g++) s += red[tid*33 + g];
    if (tid < nt){
      if (to_score) score_arr[sv[tid]] = s;
      else          outp[tid] = s;
    }
  }
}

// ---------------- launch ----------------
extern "C" void kernel_launch(void* const* d_in, const int* in_sizes, int n_in,
                              void* d_out, int out_size, void* d_ws, size_t ws_size,
                              hipStream_t stream){
  const int*   h_index       = (const int*)d_in[0];
  const int*   r_index       = (const int*)d_in[1];
  const int*   t_index       = (const int*)d_in[2];
  const float* hidden_states = (const float*)d_in[3];
  const int*   edge_index    = (const int*)d_in[4];
  const float* rel_embedding = (const float*)d_in[5];
  const float* lin_W  = (const float*)d_in[6];
  const float* lin_b  = (const float*)d_in[7];
  const float* m1_W   = (const float*)d_in[8];
  const float* m1_b   = (const float*)d_in[9];
  const float* m2_W   = (const float*)d_in[10];
  const float* m2_b   = (const float*)d_in[11];
  const float* pre_W  = (const float*)d_in[12];
  const float* pre_b  = (const float*)d_in[13];
  const float* post_W = (const float*)d_in[14];
  const float* post_b = (const float*)d_in[15];
  const float* out_W  = (const float*)d_in[16];
  const float* out_b  = (const float*)d_in[17];

  char* ws = (char*)d_ws;
  float*    hidden   = (float*)(ws + HID_OFF);
  float*    score    = (float*)(ws + SCORE_OFF);
  float*    cvec     = (float*)(ws + CVEC_OFF);
  int*      hdr      = (int*)(ws + HDR_OFF);
  unsigned long long* thr = (unsigned long long*)(ws + THR_OFF);
  unsigned* incnt    = (unsigned*)(ws + INC_OFF);
  unsigned* deg0     = (unsigned*)(ws + DEG_OFF);
  int*      node_slot= (int*)(ws + SLOT_OFF);
  float*    slot_deg = (float*)(ws + SDEG_OFF);
  float*    s1       = (float*)(ws + S1_OFF);
  float*    s2       = (float*)(ws + S2_OFF);
  unsigned* mxb      = (unsigned*)(ws + MXB_OFF);
  unsigned* mnb      = (unsigned*)(ws + MNB_OFF);
  float*    tpart    = (float*)(ws + TPART_OFF);
  int*      alist    = (int*)(ws + ALIST_OFF);
  unsigned* flag     = (unsigned*)(ws + FLAG_OFF);
  int*      tlist    = (int*)(ws + TLIST_OFF);
  int*      edges    = (int*)(ws + EDGE_OFF);
  unsigned* ctr      = (unsigned*)(ws + CTR_OFF);

  k_init<<<416, 256, 0, stream>>>(h_index, r_index, t_index, hidden_states, rel_embedding,
                                  lin_W, lin_b, m1_W, m1_b, m2_W, m2_b,
                                  hdr, cvec, hidden, score, flag, tlist, deg0, ctr);
  for (int l = 0; l < Ll; ++l){
    const float* preWl  = pre_W  + (size_t)l*2*Dd*Dd;
    const float* prebl  = pre_b  + (size_t)l*Dd;
    const float* postWl = post_W + (size_t)l*12*Dd*Dd;
    const float* postbl = post_b + (size_t)l*Dd;
    const float* outWl  = out_W  + (size_t)l*Dd*Dd;
    const float* outbl  = out_b  + (size_t)l*Dd;

    k_selzero<<<130, 256, 0, stream>>>(score, tlist, thr, s1, s2, mxb, mnb,
                                       incnt, ctr, edge_index, deg0, (l == 0) ? 1 : 0);
    k_build<<<(Ee + 255)/256, 256, 0, stream>>>(edge_index, score, thr, deg0,
                                                node_slot, alist, slot_deg, incnt,
                                                edges, ctr, flag, tlist);
    k_messages<<<384, 256, 0, stream>>>(hidden, edges, node_slot, preWl, prebl,
                                        s1, s2, mxb, mnb, ctr);
    k_post<<<256, 512, 0, stream>>>(incnt, alist, s1, s2, mxb, mnb, slot_deg,
                                    postWl, tpart, ctr);
    k_out_score<<<MAXACT/32, 256, 0, stream>>>(tpart, alist, outWl, outbl, postbl,
                                               hidden, ctr, cvec, lin_W,
                                               m1_W, m1_b, m2_W, m2_b,
                                               score, (l < Ll-1) ? 1 : 0);
    if (l == 0){
      // boundary-row score fixup: ft's init score (sc0) is stale once layer-0 selection
      // is done — the reference rescores ALL rows after each layer. Only {fh,ft} can be
      // touched-but-inactive with nonzero hidden; rescore those 4 rows once (idempotent
      // for rows k_out_score already rescored).
      k_score<<<1, 256, 0, stream>>>(hidden, cvec, lin_W, m1_W, m1_b, m2_W, m2_b,
                                     hdr, 4, (float*)d_out, score, 1);
    }
  }
  k_score<<<1, 256, 0, stream>>>(hidden, cvec, lin_W, m1_W, m1_b, m2_W, m2_b,
                                 hdr + 4, Bq*NEG, (float*)d_out, score, 0);
}

// Round 11
// 435.516 us; speedup vs baseline: 1.0494x; 1.0494x over previous
//
#include <hip/hip_runtime.h>
#include <math.h>

#define Bq 2
#define NEG 16
#define Nn 10000
#define Ee 80000
#define Dd 128
#define NUM_REL 237
#define Ll 3
#define K_SEL 1000
#define BN (Bq*Nn)
#define EPSV 1e-5f
#define MAXACT 2048
#define MAXTOUCH 8192
#define SELCAP 3328
#define LN2F 0.69314718056f

// ---------------- workspace layout (bytes) ----------------
constexpr size_t HID_OFF   = 0;                                   // BN*D f32
constexpr size_t SCORE_OFF = HID_OFF   + (size_t)BN*Dd*4;         // BN f32
constexpr size_t CVEC_OFF  = SCORE_OFF + (size_t)BN*4;            // B*D f32
constexpr size_t HDR_OFF   = CVEC_OFF  + (size_t)Bq*Dd*4;         // 64 i32
constexpr size_t THR_OFF   = HDR_OFF   + 64*4;                    // B u64
constexpr size_t INC_OFF   = THR_OFF   + Bq*8;                    // BN u32 (per-node selected-in-edge count)
constexpr size_t DEG_OFF   = INC_OFF   + (size_t)BN*4;            // Nn u32 (static out-degree, computed once)
constexpr size_t SLOT_OFF  = DEG_OFF   + (size_t)BN*4;            // BN i32
constexpr size_t CNT_OFF   = SLOT_OFF  + (size_t)BN*4;            // MAXACT u32 (unused; layout kept)
constexpr size_t SDEG_OFF  = CNT_OFF   + (size_t)MAXACT*4;        // MAXACT f32
constexpr size_t S1_OFF    = SDEG_OFF  + (size_t)MAXACT*4;        // MAXACT*D f32
constexpr size_t S2_OFF    = S1_OFF    + (size_t)MAXACT*Dd*4;
constexpr size_t MXB_OFF   = S2_OFF    + (size_t)MAXACT*Dd*4;     // MAXACT*D u32
constexpr size_t MNB_OFF   = MXB_OFF   + (size_t)MAXACT*Dd*4;
constexpr size_t TPART_OFF = MNB_OFF   + (size_t)MAXACT*Dd*4;     // 4*MAXACT*D f32
constexpr size_t ALIST_OFF = TPART_OFF + (size_t)4*MAXACT*Dd*4;   // MAXACT i32
constexpr size_t FLAG_OFF  = ALIST_OFF + (size_t)MAXACT*4;        // BN u32
constexpr size_t TLIST_OFF = FLAG_OFF  + (size_t)BN*4;            // MAXTOUCH i32
constexpr size_t EDGE_OFF  = TLIST_OFF + (size_t)MAXTOUCH*4;      // B*E*2 i32
constexpr size_t CTR_OFF   = EDGE_OFF  + (size_t)Bq*Ee*2*4;       // 16 u32
// ctr[0]=na ctr[1]=ne ctr[2]=sum(log(deg+1)) f32-bits ctr[3]=ntouched ctr[4]=sc0 f32-bits

// ---------------- helpers ----------------
__device__ __forceinline__ unsigned encf(float f){
  unsigned u = __float_as_uint(f);
  return (u & 0x80000000u) ? ~u : (u | 0x80000000u);
}
__device__ __forceinline__ float decf(unsigned e){
  unsigned u = (e & 0x80000000u) ? (e & 0x7FFFFFFFu) : ~e;
  return __uint_as_float(u);
}
__device__ __forceinline__ unsigned long long make_key(float f, int i){
  unsigned d = ~encf(f);
  return ((unsigned long long)d << 32) | (unsigned)i;
}

// ---------------- k_init: prep (block 0) || zero hidden/flag/deg0 + score fill (blocks >= 1) ----------------
__global__ __launch_bounds__(256) void k_init(
    const int* __restrict__ h_index, const int* __restrict__ r_index, const int* __restrict__ t_index,
    const float* __restrict__ hidden_states, const float* __restrict__ rel_embedding,
    const float* __restrict__ lin_W, const float* __restrict__ lin_b,
    const float* __restrict__ m1_W, const float* __restrict__ m1_b,
    const float* __restrict__ m2_W, const float* __restrict__ m2_b,
    int* __restrict__ hdr, float* __restrict__ cvec, float* __restrict__ hidden,
    float* __restrict__ score, unsigned* __restrict__ flag, int* __restrict__ tlist,
    unsigned* __restrict__ deg0, unsigned* __restrict__ ctr)
{
  __shared__ struct {
    int hbuf[Bq*NEG], tbuf[Bq*NEG], rbuf[Bq*NEG];
    int fh[Bq], ft[Bq], r0[Bq], eqf[Bq], hsrc, tsrc;
    float s0red[Dd]; float sc0;
    float relv[Bq][Dd], cv[Bq][Dd], hv[Dd], x[Bq][Dd], p[Bq][Dd];
  } sp;
  const int tid = threadIdx.x;
  const int bid = blockIdx.x;
  if (tid < Bq*NEG){
    sp.hbuf[tid] = h_index[tid];
    sp.tbuf[tid] = t_index[tid];
    sp.rbuf[tid] = r_index[tid];
  }
  if (tid < Dd) sp.s0red[tid] = fmaxf(m1_b[tid], 0.f) * m2_W[tid];
  __syncthreads();
  if (tid == 0){
    for (int b = 0; b < Bq; b++){
      bool eq = true;
      for (int j = 1; j < NEG; j++) eq = eq && (sp.hbuf[b*NEG+j] == sp.hbuf[b*NEG]);
      int h0 = eq ? sp.hbuf[b*NEG] : sp.tbuf[b*NEG];
      int t0 = eq ? sp.tbuf[b*NEG] : sp.hbuf[b*NEG];
      int r0 = eq ? sp.rbuf[b*NEG] : sp.rbuf[b*NEG] + NUM_REL;
      sp.fh[b] = h0 + b*Nn; sp.ft[b] = t0 + b*Nn;
      sp.r0[b] = r0; sp.eqf[b] = eq ? 1 : 0;
      if (b == 0){ sp.hsrc = h0; sp.tsrc = t0; }
    }
    float s = m2_b[0];
    for (int k = 0; k < Dd; k++) s += sp.s0red[k];
    sp.sc0 = s;
    if (bid == 0){
      ctr[4] = __float_as_uint(s);
      hdr[0] = sp.fh[0]; hdr[1] = sp.fh[1];
      hdr[2] = sp.ft[0]; hdr[3] = sp.ft[1];
      for (int b = 0; b < Bq; b++)
        for (int j = 0; j < NEG; j++){
          int tj = sp.eqf[b] ? sp.tbuf[b*NEG+j] : sp.hbuf[b*NEG+j];
          hdr[4 + b*NEG + j] = tj + b*Nn;
        }
      int cand[4] = { sp.ft[0], sp.fh[0], sp.ft[1], sp.fh[1] };
      int n = 0;
      for (int c = 0; c < 4; c++){
        bool dup = false;
        for (int m = 0; m < n; m++) dup = dup || (tlist[m] == cand[c]);
        if (!dup) tlist[n++] = cand[c];
        flag[cand[c]] = 1u;
      }
      ctr[3] = (unsigned)n;
    }
  }
  __syncthreads();
  const int fh0 = sp.fh[0], fh1 = sp.fh[1];
  const int ft0 = sp.ft[0], ft1 = sp.ft[1];
  const float sc0 = sp.sc0;
  if (bid == 0){
    int b = tid >> 7, d = tid & 127;
    sp.relv[b][d] = rel_embedding[(size_t)sp.r0[b]*Dd + d];
    if (b == 0) sp.hv[d] = hidden_states[(size_t)sp.hsrc*Dd + d];
    __syncthreads();
    float acc = lin_b[d];
    #pragma unroll 8
    for (int k = 0; k < Dd; k++) acc += sp.relv[b][k]*lin_W[(Dd+k)*Dd + d];
    sp.cv[b][d] = acc; cvec[b*Dd + d] = acc;
    // boundary scatter: t first, h second (h overrides; same thread => ordered)
    hidden[(size_t)sp.ft[b]*Dd + d] = hidden_states[(size_t)sp.tsrc*Dd + d];
    hidden[(size_t)sp.fh[b]*Dd + d] = hidden_states[(size_t)sp.hsrc*Dd + d];
    __syncthreads();
    float hv = sp.hv[d];
    float heur = sp.cv[b][d];
    #pragma unroll 8
    for (int k = 0; k < Dd; k++) heur += sp.hv[k]*lin_W[k*Dd + d];
    sp.x[b][d] = heur * hv;
    __syncthreads();
    float a2 = m1_b[d];
    #pragma unroll 8
    for (int k = 0; k < Dd; k++) a2 += sp.x[b][k]*m1_W[k*Dd + d];
    sp.p[b][d] = fmaxf(a2, 0.f) * m2_W[d];
    __syncthreads();
    if (tid < Bq){
      float s = m2_b[0];
      for (int k = 0; k < Dd; k++) s += sp.p[tid][k];
      score[sp.fh[tid]] = s;
    }
  } else {
    int zb = bid - 1, znb = gridDim.x - 1;
    int zt = zb*256 + tid, zs = znb*256;
    float4 z4 = make_float4(0.f, 0.f, 0.f, 0.f);
    for (int i = zt; i < BN*32; i += zs){
      int row = i >> 5;
      if (row != ft0 && row != ft1 && row != fh0 && row != fh1)
        ((float4*)hidden)[i] = z4;
    }
    for (int v = zt; v < BN; v += zs){
      if (v != ft0 && v != ft1 && v != fh0 && v != fh1) flag[v] = 0u;
      if (v != fh0 && v != fh1) score[v] = sc0;
      if (v < Nn) deg0[v] = 0u;
    }
  }
}

// ---------------- k_selzero: radix top-K (blocks 0..Bq-1) || per-layer zeroing (blocks >= Bq)
// do_deg0 (layer 0 only): zero-blocks also accumulate the static out-degree histogram.
__global__ __launch_bounds__(256) void k_selzero(
    const float* __restrict__ score, const int* __restrict__ tlist,
    unsigned long long* __restrict__ thr,
    float* __restrict__ s1, float* __restrict__ s2,
    unsigned* __restrict__ mxb, unsigned* __restrict__ mnb,
    unsigned* __restrict__ incnt, unsigned* __restrict__ ctr,
    const int* __restrict__ ei, unsigned* __restrict__ deg0, int do_deg0)
{
  int tid = threadIdx.x;
  int bid = blockIdx.x;
  if (bid < Bq){
    int b = bid;
    int nt = (int)ctr[3];
    unsigned d0 = ~encf(__uint_as_float(ctr[4]));
    __shared__ unsigned sd[SELCAP];
    __shared__ unsigned short sidx[SELCAP];
    __shared__ unsigned hist[256], histT[256];
    __shared__ int ntb_sh;
    __shared__ unsigned long long pref_sh;
    __shared__ unsigned kk_sh;
    if (tid == 0){ ntb_sh = 0; pref_sh = 0ull; kk_sh = K_SEL; }
    __syncthreads();
    int vlo = b*Nn, vhi = vlo + Nn;
    for (int i = tid; i < nt; i += 256){
      int v = tlist[i];
      if (v >= vlo && v < vhi){
        int pos = atomicAdd(&ntb_sh, 1);
        if (pos < SELCAP){
          sd[pos] = ~encf(score[v]);
          sidx[pos] = (unsigned short)(v - vlo);
        }
      }
    }
    __syncthreads();
    int ntb = min(ntb_sh, SELCAP);
    unsigned nvirt = (unsigned)(Nn - ntb);
    for (int pass = 7; pass >= 0; --pass){
      hist[tid] = 0u; histT[tid] = 0u;
      __syncthreads();
      unsigned long long pref = pref_sh;
      int sh_hi = 8*(pass+1);
      for (int j = tid; j < ntb; j += 256){
        unsigned long long key = ((unsigned long long)sd[j] << 32) | (unsigned long long)sidx[j];
        bool ok = (pass==7) || ((key >> sh_hi) == (pref >> sh_hi));
        if (ok) atomicAdd(&hist[(unsigned)(key >> (8*pass)) & 255u], 1u);
        if (pass < 4){
          unsigned idx = sidx[j];
          bool oki = (pass == 3) || ((idx >> sh_hi) == (((unsigned)pref) >> sh_hi));
          if (oki) atomicAdd(&histT[(idx >> (8*pass)) & 255u], 1u);
        }
      }
      __syncthreads();
      if (pass >= 4){
        if (tid == 0){
          unsigned long long keyv_hi = ((unsigned long long)d0 << 32);
          bool ok = (pass==7) || ((keyv_hi >> sh_hi) == (pref_sh >> sh_hi));
          if (ok) atomicAdd(&hist[(d0 >> (8*(pass-4))) & 255u], nvirt);
        }
      } else {
        if ((unsigned)(pref >> 32) == d0){
          unsigned long long hf = 0ull;
          if (pass < 3) hf = (unsigned long long)((((unsigned)pref) >> sh_hi)) << sh_hi;
          unsigned long long lo = hf + ((unsigned long long)tid << (8*pass));
          unsigned long long hi = lo + (1ull << (8*pass));
          unsigned long long nn = (unsigned long long)Nn;
          unsigned long long l2 = lo < nn ? lo : nn;
          unsigned long long h2 = hi < nn ? hi : nn;
          if (h2 > l2){
            unsigned c = (unsigned)(h2 - l2) - histT[tid];
            if (c > 0u) atomicAdd(&hist[tid], c);
          }
        }
      }
      __syncthreads();
      {
        unsigned kk = kk_sh;
        unsigned cum = 0;
        for (int i = 0; i < tid; i++) cum += hist[i];
        unsigned h = hist[tid];
        if (h > 0u && cum < kk && kk <= cum + h){
          pref_sh |= ((unsigned long long)tid) << (8*pass);
          kk_sh = kk - cum;
        }
      }
      __syncthreads();
    }
    if (tid == 0) thr[b] = pref_sh;
  } else {
    int zb = bid - Bq, znb = gridDim.x - Bq;
    int zt = zb*256 + tid, zs = znb*256;
    for (int i = zt; i < MAXACT*Dd; i += zs){
      s1[i] = 0.f; s2[i] = 0.f; mxb[i] = 0u; mnb[i] = 0xFFFFFFFFu;
    }
    for (int i = zt; i < BN; i += zs) incnt[i] = 0u;
    if (zt < 3) ctr[zt] = 0u;
    if (do_deg0){
      for (int e = zt; e < Ee; e += zs) atomicAdd(&deg0[ei[e]], 1u);
    }
  }
}

// ---------------- k_build: active-node compaction (i<BN) + edge compaction (i<Ee)
// selection & activity derived inline: sel(v) = key(score)<=thr, active(v) = sel(v) && deg0>0
__global__ void k_build(const int* __restrict__ ei, const float* __restrict__ score,
                        const unsigned long long* __restrict__ thr,
                        const unsigned* __restrict__ deg0,
                        int* __restrict__ node_slot, int* __restrict__ alist,
                        float* __restrict__ slot_deg, unsigned* __restrict__ incnt,
                        int* __restrict__ edges, unsigned* __restrict__ ctr,
                        unsigned* __restrict__ flag, int* __restrict__ tlist){
  int i = blockIdx.x*blockDim.x + threadIdx.x;
  unsigned long long th0 = thr[0], th1 = thr[1];
  if (i < BN){
    int b = (i >= Nn) ? 1 : 0;
    int v0 = i - b*Nn;
    unsigned dg = deg0[v0];
    if (dg > 0u && make_key(score[i], v0) <= (b ? th1 : th0)){
      int slot = (int)atomicAdd(&ctr[0], 1u);
      alist[slot] = i; node_slot[i] = slot; slot_deg[slot] = (float)dg;
      atomicAdd((float*)&ctr[2], logf((float)dg + 1.0f));
      if (atomicExch(&flag[i], 1u) == 0u){
        int p = (int)atomicAdd(&ctr[3], 1u);
        tlist[p] = i;
      }
    }
  }
  if (i < Ee){
    int s0 = ei[i], d0e = ei[Ee + i];
    unsigned dgd = deg0[d0e];
    if (make_key(score[s0], s0) <= th0 && dgd > 0u && make_key(score[d0e], d0e) <= th0){
      int j = (int)atomicAdd(&ctr[1], 1u);
      edges[2*j] = s0; edges[2*j+1] = d0e;
      atomicAdd(&incnt[d0e], 1u);
    }
    int sv = s0 + Nn, dv = d0e + Nn;
    if (make_key(score[sv], s0) <= th1 && dgd > 0u && make_key(score[dv], d0e) <= th1){
      int j = (int)atomicAdd(&ctr[1], 1u);
      edges[2*j] = sv; edges[2*j+1] = dv;
      atomicAdd(&incnt[dv], 1u);
    }
  }
}

// ---------------- k_messages: pre GEMV per edge, 8 edges/block, atomic aggregation ----------------
__global__ __launch_bounds__(256) void k_messages(
    const float* __restrict__ hidden, const int* __restrict__ edges,
    const int* __restrict__ node_slot,
    const float* __restrict__ preW, const float* __restrict__ preb,
    float* __restrict__ s1, float* __restrict__ s2,
    unsigned* __restrict__ mxb, unsigned* __restrict__ mnb,
    const unsigned* __restrict__ ctr){
  int ne = (int)ctr[1];
  int tid = threadIdx.x;
  int half = tid >> 7, d = tid & 127;
  __shared__ float sd[8][Dd], ss[8][Dd];
  float pb = preb[d];
  for (int j0 = blockIdx.x*8; j0 < ne; j0 += gridDim.x*8){
    int base = j0 + half*4;
    int nv = ne - base; if (nv > 4) nv = 4; if (nv < 0) nv = 0;
    int dsl[4];
    #pragma unroll
    for (int e = 0; e < 4; e++){
      int j = (e < nv) ? base + e : j0;      // dummy edges read j0 (valid), write nothing
      int s = edges[2*j]; int dv = edges[2*j+1];
      dsl[e] = node_slot[dv];
      sd[half*4+e][d] = hidden[(size_t)dv*Dd + d];
      ss[half*4+e][d] = hidden[(size_t)s*Dd + d];
    }
    __syncthreads();
    float a[4] = {pb, pb, pb, pb};
    #pragma unroll 4
    for (int k = 0; k < Dd; k++){
      float w0 = preW[k*Dd + d];
      float w1 = preW[(Dd+k)*Dd + d];
      #pragma unroll
      for (int e = 0; e < 4; e++)
        a[e] += sd[half*4+e][k]*w0 + ss[half*4+e][k]*w1;
    }
    for (int e = 0; e < nv; e++){
      int dslot = dsl[e];
      atomicAdd(&s1[dslot*Dd + d], a[e]);
      atomicAdd(&s2[dslot*Dd + d], a[e]*a[e]);
      atomicMax(&mxb[dslot*Dd + d], encf(a[e]));
      atomicMin(&mnb[dslot*Dd + d], encf(a[e]));
    }
    __syncthreads();
  }
}

// ---------------- k_post: finalize aggregators + post GEMM (tpart) ----------------
__global__ __launch_bounds__(512) void k_post(
    const unsigned* __restrict__ incnt, const int* __restrict__ alist,
    const float* __restrict__ s1, const float* __restrict__ s2,
    const unsigned* __restrict__ mxb, const unsigned* __restrict__ mnb,
    const float* __restrict__ slot_deg,
    const float* __restrict__ postW, float* __restrict__ tpart,
    const unsigned* __restrict__ ctr){
  int na = (int)ctr[0];
  int bid = blockIdx.x;
  int tile = bid & 63, ch = bid >> 6;
  if (tile*32 >= na) return;
  float logsum = __uint_as_float(ctr[2]);
  float avg = (logsum + (float)(BN - na)*LN2F) / (float)BN;
  __shared__ float lb[32*136];
  __shared__ float wbuf[3*16*128];
  __shared__ float sden[32];
  __shared__ unsigned shas[32];
  int tid = threadIdx.x;
  if (tid < 32){
    int slot = tile*32 + tid;
    unsigned c = (slot < na) ? incnt[alist[slot]] : 0u;
    sden[tid] = fmaxf((float)c, 1.0f);
    shas[tid] = c;
  }
  __syncthreads();
  for (int idx = tid; idx < 32*Dd; idx += 512){
    int sl = idx >> 7, kk = idx & 127;
    int gi = (tile*32 + sl)*Dd + kk;
    float den = sden[sl];
    float val;
    if (ch == 0)      val = s1[gi]/den;
    else if (ch == 1) val = shas[sl] ? decf(mxb[gi]) : 0.f;
    else if (ch == 2) val = shas[sl] ? decf(mnb[gi]) : 0.f;
    else {
      float mv = s1[gi]/den;
      float var = s2[gi]/den - mv*mv;
      val = sqrtf(fmaxf(var, 0.f) + EPSV);
    }
    lb[sl*136 + kk] = val;
  }
  int cg = tid & 31, rg = tid >> 5;        // 32 col-groups x 16 row-groups (2 rows)
  int c0 = cg*4;
  float a0[2][4], a1[2][4], a2[2][4];
  #pragma unroll
  for (int i = 0; i < 2; i++)
    #pragma unroll
    for (int j = 0; j < 4; j++){ a0[i][j]=0.f; a1[i][j]=0.f; a2[i][j]=0.f; }
  for (int chunk = 0; chunk < 8; ++chunk){
    #pragma unroll
    for (int i = 0; i < 3; ++i){
      int f = tid + i*512;                 // 1536 float4
      int q = f >> 9, r = f & 511;
      int kk = r >> 5, c4 = r & 31;
      int grow = q*512 + ch*128 + chunk*16 + kk;
      ((float4*)wbuf)[f] = *(const float4*)(postW + (size_t)grow*Dd + c4*4);
    }
    __syncthreads();
    #pragma unroll
    for (int k4 = 0; k4 < 4; ++k4){
      float4 av0 = *(const float4*)&lb[(rg*2+0)*136 + chunk*16 + k4*4];
      float4 av1 = *(const float4*)&lb[(rg*2+1)*136 + chunk*16 + k4*4];
      #pragma unroll
      for (int j = 0; j < 4; ++j){
        int kk = k4*4 + j;
        float4 w0 = *(const float4*)&wbuf[kk*128 + c0];
        float4 w1 = *(const float4*)&wbuf[(16+kk)*128 + c0];
        float4 w2 = *(const float4*)&wbuf[(32+kk)*128 + c0];
        float av[2] = { (&av0.x)[j], (&av1.x)[j] };
        #pragma unroll
        for (int i = 0; i < 2; i++){
          float a = av[i];
          a0[i][0] += a*w0.x; a0[i][1] += a*w0.y; a0[i][2] += a*w0.z; a0[i][3] += a*w0.w;
          a1[i][0] += a*w1.x; a1[i][1] += a*w1.y; a1[i][2] += a*w1.z; a1[i][3] += a*w1.w;
          a2[i][0] += a*w2.x; a2[i][1] += a*w2.y; a2[i][2] += a*w2.z; a2[i][3] += a*w2.w;
        }
      }
    }
    __syncthreads();
  }
  #pragma unroll
  for (int i = 0; i < 2; i++){
    int slot = tile*32 + rg*2 + i;
    if (slot < na){
      float dg = slot_deg[slot];
      float logd = logf(dg + 1.f);
      float al = logd/avg, be = avg/logd;
      float4 r;
      r.x = a0[i][0] + al*a1[i][0] + be*a2[i][0];
      r.y = a0[i][1] + al*a1[i][1] + be*a2[i][1];
      r.z = a0[i][2] + al*a1[i][2] + be*a2[i][2];
      r.w = a0[i][3] + al*a1[i][3] + be*a2[i][3];
      *(float4*)(tpart + (size_t)ch*MAXACT*Dd + (size_t)slot*Dd + c0) = r;
    }
  }
}

// ---------------- k_out_resid: out GEMM + residual ----------------
__global__ __launch_bounds__(256) void k_out_resid(
    const float* __restrict__ tpart, const int* __restrict__ alist,
    const float* __restrict__ outW, const float* __restrict__ outb,
    const float* __restrict__ postb, float* __restrict__ hidden,
    const unsigned* __restrict__ ctr){
  int na = (int)ctr[0];
  int tile = blockIdx.x;
  if (tile*32 >= na) return;
  __shared__ float tr[32*136];
  __shared__ float wbuf[16*128];
  int tid = threadIdx.x;
  for (int idx = tid; idx < 32*Dd; idx += 256){
    int sl = idx >> 7, kk = idx & 127;
    size_t o = (size_t)(tile*32 + sl)*Dd + kk;
    tr[sl*136 + kk] = tpart[o] + tpart[(size_t)MAXACT*Dd + o]
                    + tpart[(size_t)2*MAXACT*Dd + o] + tpart[(size_t)3*MAXACT*Dd + o]
                    + postb[kk];
  }
  int cg = tid & 31, rg = tid >> 5;        // 32 col-groups x 8 row-groups (4 rows)
  int c0 = cg*4;
  float4 ob = *(const float4*)(outb + c0);
  float acc[4][4];
  #pragma unroll
  for (int r = 0; r < 4; r++){ acc[r][0]=ob.x; acc[r][1]=ob.y; acc[r][2]=ob.z; acc[r][3]=ob.w; }
  for (int chunk = 0; chunk < 8; ++chunk){
    #pragma unroll
    for (int i = 0; i < 2; ++i){
      int f = tid + i*256;                 // 512 float4
      int kk = f >> 5, c4 = f & 31;
      ((float4*)wbuf)[f] = *(const float4*)(outW + (size_t)(chunk*16 + kk)*Dd + c4*4);
    }
    __syncthreads();
    #pragma unroll
    for (int k4 = 0; k4 < 4; ++k4){
      float4 av[4];
      #pragma unroll
      for (int r = 0; r < 4; r++)
        av[r] = *(const float4*)&tr[(rg*4+r)*136 + chunk*16 + k4*4];
      #pragma unroll
      for (int j = 0; j < 4; ++j){
        float4 w = *(const float4*)&wbuf[(k4*4+j)*128 + c0];
        #pragma unroll
        for (int r = 0; r < 4; r++){
          float a = (&av[r].x)[j];
          acc[r][0] += a*w.x; acc[r][1] += a*w.y; acc[r][2] += a*w.z; acc[r][3] += a*w.w;
        }
      }
    }
    __syncthreads();
  }
  #pragma unroll
  for (int r = 0; r < 4; r++){
    int slot = tile*32 + rg*4 + r;
    if (slot < na){
      int v = alist[slot];
      float* hp = hidden + (size_t)v*Dd + c0;
      float4 h4 = *(float4*)hp;
      h4.x += acc[r][0]; h4.y += acc[r][1]; h4.z += acc[r][2]; h4.w += acc[r][3];
      *(float4*)hp = h4;
    }
  }
}

// ---------------- k_score: score rows from a list; ovr path writes d_out directly ----------------
__global__ __launch_bounds__(256) void k_score(
    const float* __restrict__ hidden, const float* __restrict__ cvec,
    const float* __restrict__ linW,
    const float* __restrict__ m1W, const float* __restrict__ m1b,
    const float* __restrict__ m2W, const float* __restrict__ m2b,
    const int* __restrict__ tlist, const unsigned* __restrict__ ctr,
    float* __restrict__ score,
    const int* __restrict__ ovr, int ovr_n, float* __restrict__ outp){
  int nt = (ovr_n > 0) ? ovr_n : (int)ctr[3];
  const int* list = (ovr_n > 0) ? ovr : tlist;
  int nb = blockIdx.x * 32;
  if (nb >= nt) return;
  __shared__ float sh[32*Dd];
  __shared__ float sx[32*Dd];
  __shared__ float sc[2*Dd];
  __shared__ int   sv[32];
  __shared__ float red[32*33];
  int tid = threadIdx.x;
  if (tid < 32){
    int idx = nb + tid;
    sv[tid] = (idx < nt) ? list[idx] : list[nb];
  }
  sc[tid] = cvec[tid];
  __syncthreads();
  for (int q = tid; q < 32*32; q += 256){
    int row = q >> 5, f4 = q & 31;
    ((float4*)sh)[row*32 + f4] = ((const float4*)(hidden + (size_t)sv[row]*Dd))[f4];
  }
  __syncthreads();
  int cg = tid & 31, rg = tid >> 5;
  int c0 = cg*4;
  float acc[4][4];
  #pragma unroll
  for (int i = 0; i < 4; i++){ acc[i][0]=0.f; acc[i][1]=0.f; acc[i][2]=0.f; acc[i][3]=0.f; }
  for (int k4 = 0; k4 < 32; k4++){
    float4 av[4];
    #pragma unroll
    for (int i = 0; i < 4; i++) av[i] = ((float4*)sh)[(rg*4+i)*32 + k4];
    #pragma unroll
    for (int j = 0; j < 4; j++){
      float4 w = *(const float4*)(linW + (size_t)(k4*4+j)*Dd + c0);
      #pragma unroll
      for (int i = 0; i < 4; i++){
        float a = (&av[i].x)[j];
        acc[i][0] += a*w.x; acc[i][1] += a*w.y; acc[i][2] += a*w.z; acc[i][3] += a*w.w;
      }
    }
  }
  #pragma unroll
  for (int i = 0; i < 4; i++){
    int row = rg*4 + i;
    int bb = (sv[row] >= Nn) ? 1 : 0;
    float4 cv = *(float4*)&sc[bb*Dd + c0];
    float4 hv = ((float4*)sh)[row*32 + cg];
    float4 x;
    x.x = (acc[i][0] + cv.x)*hv.x;
    x.y = (acc[i][1] + cv.y)*hv.y;
    x.z = (acc[i][2] + cv.z)*hv.z;
    x.w = (acc[i][3] + cv.w)*hv.w;
    ((float4*)sx)[row*32 + cg] = x;
  }
  __syncthreads();
  #pragma unroll
  for (int i = 0; i < 4; i++){ acc[i][0]=0.f; acc[i][1]=0.f; acc[i][2]=0.f; acc[i][3]=0.f; }
  for (int k4 = 0; k4 < 32; k4++){
    float4 av[4];
    #pragma unroll
    for (int i = 0; i < 4; i++) av[i] = ((float4*)sx)[(rg*4+i)*32 + k4];
    #pragma unroll
    for (int j = 0; j < 4; j++){
      float4 w = *(const float4*)(m1W + (size_t)(k4*4+j)*Dd + c0);
      #pragma unroll
      for (int i = 0; i < 4; i++){
        float a = (&av[i].x)[j];
        acc[i][0] += a*w.x; acc[i][1] += a*w.y; acc[i][2] += a*w.z; acc[i][3] += a*w.w;
      }
    }
  }
  float4 mb = *(const float4*)(m1b + c0);
  float4 mw = *(const float4*)(m2W + c0);
  #pragma unroll
  for (int i = 0; i < 4; i++){
    float p0 = fmaxf(acc[i][0]+mb.x, 0.f)*mw.x;
    float p1 = fmaxf(acc[i][1]+mb.y, 0.f)*mw.y;
    float p2 = fmaxf(acc[i][2]+mb.z, 0.f)*mw.z;
    float p3 = fmaxf(acc[i][3]+mb.w, 0.f)*mw.w;
    red[(rg*4+i)*33 + cg] = p0+p1+p2+p3;
  }
  __syncthreads();
  if (tid < 32){
    float s = m2b[0];
    for (int g = 0; g < 32; g++) s += red[tid*33 + g];
    if (nb + tid < nt){
      if (ovr_n > 0) outp[nb + tid] = s;
      else           score[sv[tid]] = s;
    }
  }
}

// ---------------- launch ----------------
extern "C" void kernel_launch(void* const* d_in, const int* in_sizes, int n_in,
                              void* d_out, int out_size, void* d_ws, size_t ws_size,
                              hipStream_t stream){
  const int*   h_index       = (const int*)d_in[0];
  const int*   r_index       = (const int*)d_in[1];
  const int*   t_index       = (const int*)d_in[2];
  const float* hidden_states = (const float*)d_in[3];
  const int*   edge_index    = (const int*)d_in[4];
  const float* rel_embedding = (const float*)d_in[5];
  const float* lin_W  = (const float*)d_in[6];
  const float* lin_b  = (const float*)d_in[7];
  const float* m1_W   = (const float*)d_in[8];
  const float* m1_b   = (const float*)d_in[9];
  const float* m2_W   = (const float*)d_in[10];
  const float* m2_b   = (const float*)d_in[11];
  const float* pre_W  = (const float*)d_in[12];
  const float* pre_b  = (const float*)d_in[13];
  const float* post_W = (const float*)d_in[14];
  const float* post_b = (const float*)d_in[15];
  const float* out_W  = (const float*)d_in[16];
  const float* out_b  = (const float*)d_in[17];

  char* ws = (char*)d_ws;
  float*    hidden   = (float*)(ws + HID_OFF);
  float*    score    = (float*)(ws + SCORE_OFF);
  float*    cvec     = (float*)(ws + CVEC_OFF);
  int*      hdr      = (int*)(ws + HDR_OFF);
  unsigned long long* thr = (unsigned long long*)(ws + THR_OFF);
  unsigned* incnt    = (unsigned*)(ws + INC_OFF);
  unsigned* deg0     = (unsigned*)(ws + DEG_OFF);
  int*      node_slot= (int*)(ws + SLOT_OFF);
  float*    slot_deg = (float*)(ws + SDEG_OFF);
  float*    s1       = (float*)(ws + S1_OFF);
  float*    s2       = (float*)(ws + S2_OFF);
  unsigned* mxb      = (unsigned*)(ws + MXB_OFF);
  unsigned* mnb      = (unsigned*)(ws + MNB_OFF);
  float*    tpart    = (float*)(ws + TPART_OFF);
  int*      alist    = (int*)(ws + ALIST_OFF);
  unsigned* flag     = (unsigned*)(ws + FLAG_OFF);
  int*      tlist    = (int*)(ws + TLIST_OFF);
  int*      edges    = (int*)(ws + EDGE_OFF);
  unsigned* ctr      = (unsigned*)(ws + CTR_OFF);

  k_init<<<416, 256, 0, stream>>>(h_index, r_index, t_index, hidden_states, rel_embedding,
                                  lin_W, lin_b, m1_W, m1_b, m2_W, m2_b,
                                  hdr, cvec, hidden, score, flag, tlist, deg0, ctr);
  for (int l = 0; l < Ll; ++l){
    const float* preWl  = pre_W  + (size_t)l*2*Dd*Dd;
    const float* prebl  = pre_b  + (size_t)l*Dd;
    const float* postWl = post_W + (size_t)l*12*Dd*Dd;
    const float* postbl = post_b + (size_t)l*Dd;
    const float* outWl  = out_W  + (size_t)l*Dd*Dd;
    const float* outbl  = out_b  + (size_t)l*Dd;

    k_selzero<<<130, 256, 0, stream>>>(score, tlist, thr, s1, s2, mxb, mnb,
                                       incnt, ctr, edge_index, deg0, (l == 0) ? 1 : 0);
    k_build<<<(Ee + 255)/256, 256, 0, stream>>>(edge_index, score, thr, deg0,
                                                node_slot, alist, slot_deg, incnt,
                                                edges, ctr, flag, tlist);
    k_messages<<<384, 256, 0, stream>>>(hidden, edges, node_slot, preWl, prebl,
                                        s1, s2, mxb, mnb, ctr);
    k_post<<<256, 512, 0, stream>>>(incnt, alist, s1, s2, mxb, mnb, slot_deg,
                                    postWl, tpart, ctr);
    k_out_resid<<<MAXACT/32, 256, 0, stream>>>(tpart, alist, outWl, outbl, postbl,
                                               hidden, ctr);
    if (l < Ll-1){
      k_score<<<MAXTOUCH/32, 256, 0, stream>>>(hidden, cvec, lin_W, m1_W, m1_b, m2_W, m2_b,
                                               tlist, ctr, score, tlist, 0, score);
    } else {
      k_score<<<1, 256, 0, stream>>>(hidden, cvec, lin_W, m1_W, m1_b, m2_W, m2_b,
                                     tlist, ctr, score, hdr + 4, Bq*NEG, (float*)d_out);
    }
  }
}

// Round 17
// 428.944 us; speedup vs baseline: 1.0655x; 1.0153x over previous
//
#include <hip/hip_runtime.h>
#include <math.h>

#define Bq 2
#define NEG 16
#define Nn 10000
#define Ee 80000
#define Dd 128
#define NUM_REL 237
#define Ll 3
#define K_SEL 1000
#define BN (Bq*Nn)
#define EPSV 1e-5f
#define MAXACT 2048
#define MAXTOUCH 8192
#define SELCAP 3328
#define LN2F 0.69314718056f

// ---------------- workspace layout (bytes) ----------------
constexpr size_t HID_OFF   = 0;                                   // BN*D f32
constexpr size_t SCORE_OFF = HID_OFF   + (size_t)BN*Dd*4;         // BN f32
constexpr size_t CVEC_OFF  = SCORE_OFF + (size_t)BN*4;            // B*D f32
constexpr size_t HDR_OFF   = CVEC_OFF  + (size_t)Bq*Dd*4;         // 64 i32
constexpr size_t THR_OFF   = HDR_OFF   + 64*4;                    // B u64
constexpr size_t INC_OFF   = THR_OFF   + Bq*8;                    // BN u32 (per-node selected-in-edge count)
constexpr size_t DEG_OFF   = INC_OFF   + (size_t)BN*4;            // Nn u32 (static out-degree, computed once)
constexpr size_t SLOT_OFF  = DEG_OFF   + (size_t)BN*4;            // BN i32
constexpr size_t CNT_OFF   = SLOT_OFF  + (size_t)BN*4;            // MAXACT u32 (unused; layout kept)
constexpr size_t SDEG_OFF  = CNT_OFF   + (size_t)MAXACT*4;        // MAXACT f32
constexpr size_t S1_OFF    = SDEG_OFF  + (size_t)MAXACT*4;        // MAXACT*D f32
constexpr size_t S2_OFF    = S1_OFF    + (size_t)MAXACT*Dd*4;
constexpr size_t MXB_OFF   = S2_OFF    + (size_t)MAXACT*Dd*4;     // MAXACT*D u32
constexpr size_t MNB_OFF   = MXB_OFF   + (size_t)MAXACT*Dd*4;
constexpr size_t TPART_OFF = MNB_OFF   + (size_t)MAXACT*Dd*4;     // 4*MAXACT*D f32
constexpr size_t ALIST_OFF = TPART_OFF + (size_t)4*MAXACT*Dd*4;   // MAXACT i32
constexpr size_t FLAG_OFF  = ALIST_OFF + (size_t)MAXACT*4;        // BN u32
constexpr size_t TLIST_OFF = FLAG_OFF  + (size_t)BN*4;            // MAXTOUCH i32
constexpr size_t EDGE_OFF  = TLIST_OFF + (size_t)MAXTOUCH*4;      // B*E*2 i32
constexpr size_t CTR_OFF   = EDGE_OFF  + (size_t)Bq*Ee*2*4;       // 16 u32
// ctr[0]=na ctr[1]=ne ctr[2]=sum(log(deg+1)) f32-bits ctr[3]=ntouched ctr[4]=sc0 f32-bits

// ---------------- helpers ----------------
__device__ __forceinline__ unsigned encf(float f){
  unsigned u = __float_as_uint(f);
  return (u & 0x80000000u) ? ~u : (u | 0x80000000u);
}
__device__ __forceinline__ float decf(unsigned e){
  unsigned u = (e & 0x80000000u) ? (e & 0x7FFFFFFFu) : ~e;
  return __uint_as_float(u);
}
__device__ __forceinline__ unsigned long long make_key(float f, int i){
  unsigned d = ~encf(f);
  return ((unsigned long long)d << 32) | (unsigned)i;
}

// ---------------- k_init: prep (block 0) || zero hidden/flag/deg0 + score fill (blocks >= 1) ----------------
__global__ __launch_bounds__(256) void k_init(
    const int* __restrict__ h_index, const int* __restrict__ r_index, const int* __restrict__ t_index,
    const float* __restrict__ hidden_states, const float* __restrict__ rel_embedding,
    const float* __restrict__ lin_W, const float* __restrict__ lin_b,
    const float* __restrict__ m1_W, const float* __restrict__ m1_b,
    const float* __restrict__ m2_W, const float* __restrict__ m2_b,
    int* __restrict__ hdr, float* __restrict__ cvec, float* __restrict__ hidden,
    float* __restrict__ score, unsigned* __restrict__ flag, int* __restrict__ tlist,
    unsigned* __restrict__ deg0, unsigned* __restrict__ ctr)
{
  __shared__ struct {
    int hbuf[Bq*NEG], tbuf[Bq*NEG], rbuf[Bq*NEG];
    int fh[Bq], ft[Bq], r0[Bq], eqf[Bq], hsrc, tsrc;
    float s0red[Dd]; float sc0;
    float relv[Bq][Dd], cv[Bq][Dd], hv[Dd], x[Bq][Dd], p[Bq][Dd];
  } sp;
  const int tid = threadIdx.x;
  const int bid = blockIdx.x;
  if (tid < Bq*NEG){
    sp.hbuf[tid] = h_index[tid];
    sp.tbuf[tid] = t_index[tid];
    sp.rbuf[tid] = r_index[tid];
  }
  if (tid < Dd) sp.s0red[tid] = fmaxf(m1_b[tid], 0.f) * m2_W[tid];
  __syncthreads();
  if (tid == 0){
    for (int b = 0; b < Bq; b++){
      bool eq = true;
      for (int j = 1; j < NEG; j++) eq = eq && (sp.hbuf[b*NEG+j] == sp.hbuf[b*NEG]);
      int h0 = eq ? sp.hbuf[b*NEG] : sp.tbuf[b*NEG];
      int t0 = eq ? sp.tbuf[b*NEG] : sp.hbuf[b*NEG];
      int r0 = eq ? sp.rbuf[b*NEG] : sp.rbuf[b*NEG] + NUM_REL;
      sp.fh[b] = h0 + b*Nn; sp.ft[b] = t0 + b*Nn;
      sp.r0[b] = r0; sp.eqf[b] = eq ? 1 : 0;
      if (b == 0){ sp.hsrc = h0; sp.tsrc = t0; }
    }
    float s = m2_b[0];
    for (int k = 0; k < Dd; k++) s += sp.s0red[k];
    sp.sc0 = s;
    if (bid == 0){
      ctr[4] = __float_as_uint(s);
      hdr[0] = sp.fh[0]; hdr[1] = sp.fh[1];
      hdr[2] = sp.ft[0]; hdr[3] = sp.ft[1];
      for (int b = 0; b < Bq; b++)
        for (int j = 0; j < NEG; j++){
          int tj = sp.eqf[b] ? sp.tbuf[b*NEG+j] : sp.hbuf[b*NEG+j];
          hdr[4 + b*NEG + j] = tj + b*Nn;
        }
      int cand[4] = { sp.ft[0], sp.fh[0], sp.ft[1], sp.fh[1] };
      int n = 0;
      for (int c = 0; c < 4; c++){
        bool dup = false;
        for (int m = 0; m < n; m++) dup = dup || (tlist[m] == cand[c]);
        if (!dup) tlist[n++] = cand[c];
        flag[cand[c]] = 1u;
      }
      ctr[3] = (unsigned)n;
    }
  }
  __syncthreads();
  const int fh0 = sp.fh[0], fh1 = sp.fh[1];
  const int ft0 = sp.ft[0], ft1 = sp.ft[1];
  const float sc0 = sp.sc0;
  if (bid == 0){
    int b = tid >> 7, d = tid & 127;
    sp.relv[b][d] = rel_embedding[(size_t)sp.r0[b]*Dd + d];
    if (b == 0) sp.hv[d] = hidden_states[(size_t)sp.hsrc*Dd + d];
    __syncthreads();
    float acc = lin_b[d];
    #pragma unroll 8
    for (int k = 0; k < Dd; k++) acc += sp.relv[b][k]*lin_W[(Dd+k)*Dd + d];
    sp.cv[b][d] = acc; cvec[b*Dd + d] = acc;
    // boundary scatter: t first, h second (h overrides; same thread => ordered)
    hidden[(size_t)sp.ft[b]*Dd + d] = hidden_states[(size_t)sp.tsrc*Dd + d];
    hidden[(size_t)sp.fh[b]*Dd + d] = hidden_states[(size_t)sp.hsrc*Dd + d];
    __syncthreads();
    float hv = sp.hv[d];
    float heur = sp.cv[b][d];
    #pragma unroll 8
    for (int k = 0; k < Dd; k++) heur += sp.hv[k]*lin_W[k*Dd + d];
    sp.x[b][d] = heur * hv;
    __syncthreads();
    float a2 = m1_b[d];
    #pragma unroll 8
    for (int k = 0; k < Dd; k++) a2 += sp.x[b][k]*m1_W[k*Dd + d];
    sp.p[b][d] = fmaxf(a2, 0.f) * m2_W[d];
    __syncthreads();
    if (tid < Bq){
      float s = m2_b[0];
      for (int k = 0; k < Dd; k++) s += sp.p[tid][k];
      score[sp.fh[tid]] = s;
    }
  } else {
    int zb = bid - 1, znb = gridDim.x - 1;
    int zt = zb*256 + tid, zs = znb*256;
    float4 z4 = make_float4(0.f, 0.f, 0.f, 0.f);
    for (int i = zt; i < BN*32; i += zs){
      int row = i >> 5;
      if (row != ft0 && row != ft1 && row != fh0 && row != fh1)
        ((float4*)hidden)[i] = z4;
    }
    for (int v = zt; v < BN; v += zs){
      if (v != ft0 && v != ft1 && v != fh0 && v != fh1) flag[v] = 0u;
      if (v != fh0 && v != fh1) score[v] = sc0;
      if (v < Nn) deg0[v] = 0u;
    }
  }
}

// ---------------- k_selzero: radix top-K (blocks 0..Bq-1) || per-layer zeroing (blocks >= Bq)
// do_deg0 (layer 0 only): zero-blocks also accumulate the static out-degree histogram.
__global__ __launch_bounds__(256) void k_selzero(
    const float* __restrict__ score, const int* __restrict__ tlist,
    unsigned long long* __restrict__ thr,
    float* __restrict__ s1, float* __restrict__ s2,
    unsigned* __restrict__ mxb, unsigned* __restrict__ mnb,
    unsigned* __restrict__ incnt, unsigned* __restrict__ ctr,
    const int* __restrict__ ei, unsigned* __restrict__ deg0, int do_deg0)
{
  int tid = threadIdx.x;
  int bid = blockIdx.x;
  if (bid < Bq){
    int b = bid;
    int nt = (int)ctr[3];
    unsigned d0 = ~encf(__uint_as_float(ctr[4]));
    __shared__ unsigned sd[SELCAP];
    __shared__ unsigned short sidx[SELCAP];
    __shared__ unsigned hist[256], histT[256];
    __shared__ int ntb_sh;
    __shared__ unsigned long long pref_sh;
    __shared__ unsigned kk_sh;
    if (tid == 0){ ntb_sh = 0; pref_sh = 0ull; kk_sh = K_SEL; }
    __syncthreads();
    int vlo = b*Nn, vhi = vlo + Nn;
    for (int i = tid; i < nt; i += 256){
      int v = tlist[i];
      if (v >= vlo && v < vhi){
        int pos = atomicAdd(&ntb_sh, 1);
        if (pos < SELCAP){
          sd[pos] = ~encf(score[v]);
          sidx[pos] = (unsigned short)(v - vlo);
        }
      }
    }
    __syncthreads();
    int ntb = min(ntb_sh, SELCAP);
    unsigned nvirt = (unsigned)(Nn - ntb);
    for (int pass = 7; pass >= 0; --pass){
      hist[tid] = 0u; histT[tid] = 0u;
      __syncthreads();
      unsigned long long pref = pref_sh;
      int sh_hi = 8*(pass+1);
      for (int j = tid; j < ntb; j += 256){
        unsigned long long key = ((unsigned long long)sd[j] << 32) | (unsigned long long)sidx[j];
        bool ok = (pass==7) || ((key >> sh_hi) == (pref >> sh_hi));
        if (ok) atomicAdd(&hist[(unsigned)(key >> (8*pass)) & 255u], 1u);
        if (pass < 4){
          unsigned idx = sidx[j];
          bool oki = (pass == 3) || ((idx >> sh_hi) == (((unsigned)pref) >> sh_hi));
          if (oki) atomicAdd(&histT[(idx >> (8*pass)) & 255u], 1u);
        }
      }
      __syncthreads();
      if (pass >= 4){
        if (tid == 0){
          unsigned long long keyv_hi = ((unsigned long long)d0 << 32);
          bool ok = (pass==7) || ((keyv_hi >> sh_hi) == (pref_sh >> sh_hi));
          if (ok) atomicAdd(&hist[(d0 >> (8*(pass-4))) & 255u], nvirt);
        }
      } else {
        if ((unsigned)(pref >> 32) == d0){
          unsigned long long hf = 0ull;
          if (pass < 3) hf = (unsigned long long)((((unsigned)pref) >> sh_hi)) << sh_hi;
          unsigned long long lo = hf + ((unsigned long long)tid << (8*pass));
          unsigned long long hi = lo + (1ull << (8*pass));
          unsigned long long nn = (unsigned long long)Nn;
          unsigned long long l2 = lo < nn ? lo : nn;
          unsigned long long h2 = hi < nn ? hi : nn;
          if (h2 > l2){
            unsigned c = (unsigned)(h2 - l2) - histT[tid];
            if (c > 0u) atomicAdd(&hist[tid], c);
          }
        }
      }
      __syncthreads();
      {
        unsigned kk = kk_sh;
        unsigned cum = 0;
        for (int i = 0; i < tid; i++) cum += hist[i];
        unsigned h = hist[tid];
        if (h > 0u && cum < kk && kk <= cum + h){
          pref_sh |= ((unsigned long long)tid) << (8*pass);
          kk_sh = kk - cum;
        }
      }
      __syncthreads();
    }
    if (tid == 0) thr[b] = pref_sh;
  } else {
    int zb = bid - Bq, znb = gridDim.x - Bq;
    int zt = zb*256 + tid, zs = znb*256;
    for (int i = zt; i < MAXACT*Dd; i += zs){
      s1[i] = 0.f; s2[i] = 0.f; mxb[i] = 0u; mnb[i] = 0xFFFFFFFFu;
    }
    for (int i = zt; i < BN; i += zs) incnt[i] = 0u;
    if (zt < 3) ctr[zt] = 0u;
    if (do_deg0){
      for (int e = zt; e < Ee; e += zs) atomicAdd(&deg0[ei[e]], 1u);
    }
  }
}

// ---------------- k_build: active-node compaction (i<BN) + edge compaction (i<Ee)
// selection & activity derived inline: sel(v) = key(score)<=thr, active(v) = sel(v) && deg0>0
__global__ void k_build(const int* __restrict__ ei, const float* __restrict__ score,
                        const unsigned long long* __restrict__ thr,
                        const unsigned* __restrict__ deg0,
                        int* __restrict__ node_slot, int* __restrict__ alist,
                        float* __restrict__ slot_deg, unsigned* __restrict__ incnt,
                        int* __restrict__ edges, unsigned* __restrict__ ctr,
                        unsigned* __restrict__ flag, int* __restrict__ tlist){
  int i = blockIdx.x*blockDim.x + threadIdx.x;
  unsigned long long th0 = thr[0], th1 = thr[1];
  if (i < BN){
    int b = (i >= Nn) ? 1 : 0;
    int v0 = i - b*Nn;
    unsigned dg = deg0[v0];
    if (dg > 0u && make_key(score[i], v0) <= (b ? th1 : th0)){
      int slot = (int)atomicAdd(&ctr[0], 1u);
      alist[slot] = i; node_slot[i] = slot; slot_deg[slot] = (float)dg;
      atomicAdd((float*)&ctr[2], logf((float)dg + 1.0f));
      if (atomicExch(&flag[i], 1u) == 0u){
        int p = (int)atomicAdd(&ctr[3], 1u);
        tlist[p] = i;
      }
    }
  }
  if (i < Ee){
    int s0 = ei[i], d0e = ei[Ee + i];
    unsigned dgd = deg0[d0e];
    if (make_key(score[s0], s0) <= th0 && dgd > 0u && make_key(score[d0e], d0e) <= th0){
      int j = (int)atomicAdd(&ctr[1], 1u);
      edges[2*j] = s0; edges[2*j+1] = d0e;
      atomicAdd(&incnt[d0e], 1u);
    }
    int sv = s0 + Nn, dv = d0e + Nn;
    if (make_key(score[sv], s0) <= th1 && dgd > 0u && make_key(score[dv], d0e) <= th1){
      int j = (int)atomicAdd(&ctr[1], 1u);
      edges[2*j] = sv; edges[2*j+1] = dv;
      atomicAdd(&incnt[dv], 1u);
    }
  }
}

// ---------------- k_messages: pre GEMV per edge, 8 edges/block, atomic aggregation ----------------
__global__ __launch_bounds__(256) void k_messages(
    const float* __restrict__ hidden, const int* __restrict__ edges,
    const int* __restrict__ node_slot,
    const float* __restrict__ preW, const float* __restrict__ preb,
    float* __restrict__ s1, float* __restrict__ s2,
    unsigned* __restrict__ mxb, unsigned* __restrict__ mnb,
    const unsigned* __restrict__ ctr){
  int ne = (int)ctr[1];
  int tid = threadIdx.x;
  int half = tid >> 7, d = tid & 127;
  __shared__ float sd[8][Dd], ss[8][Dd];
  float pb = preb[d];
  for (int j0 = blockIdx.x*8; j0 < ne; j0 += gridDim.x*8){
    int base = j0 + half*4;
    int nv = ne - base; if (nv > 4) nv = 4; if (nv < 0) nv = 0;
    int dsl[4];
    #pragma unroll
    for (int e = 0; e < 4; e++){
      int j = (e < nv) ? base + e : j0;      // dummy edges read j0 (valid), write nothing
      int s = edges[2*j]; int dv = edges[2*j+1];
      dsl[e] = node_slot[dv];
      sd[half*4+e][d] = hidden[(size_t)dv*Dd + d];
      ss[half*4+e][d] = hidden[(size_t)s*Dd + d];
    }
    __syncthreads();
    float a[4] = {pb, pb, pb, pb};
    #pragma unroll 4
    for (int k = 0; k < Dd; k++){
      float w0 = preW[k*Dd + d];
      float w1 = preW[(Dd+k)*Dd + d];
      #pragma unroll
      for (int e = 0; e < 4; e++)
        a[e] += sd[half*4+e][k]*w0 + ss[half*4+e][k]*w1;
    }
    for (int e = 0; e < nv; e++){
      int dslot = dsl[e];
      atomicAdd(&s1[dslot*Dd + d], a[e]);
      atomicAdd(&s2[dslot*Dd + d], a[e]*a[e]);
      atomicMax(&mxb[dslot*Dd + d], encf(a[e]));
      atomicMin(&mnb[dslot*Dd + d], encf(a[e]));
    }
    __syncthreads();
  }
}

// ---------------- k_post: finalize aggregators + post GEMM (tpart) ----------------
__global__ __launch_bounds__(512) void k_post(
    const unsigned* __restrict__ incnt, const int* __restrict__ alist,
    const float* __restrict__ s1, const float* __restrict__ s2,
    const unsigned* __restrict__ mxb, const unsigned* __restrict__ mnb,
    const float* __restrict__ slot_deg,
    const float* __restrict__ postW, float* __restrict__ tpart,
    const unsigned* __restrict__ ctr){
  int na = (int)ctr[0];
  int bid = blockIdx.x;
  int tile = bid & 63, ch = bid >> 6;
  if (tile*32 >= na) return;
  float logsum = __uint_as_float(ctr[2]);
  float avg = (logsum + (float)(BN - na)*LN2F) / (float)BN;
  __shared__ float lb[32*136];
  __shared__ float wbuf[3*16*128];
  __shared__ float sden[32];
  __shared__ unsigned shas[32];
  int tid = threadIdx.x;
  if (tid < 32){
    int slot = tile*32 + tid;
    unsigned c = (slot < na) ? incnt[alist[slot]] : 0u;
    sden[tid] = fmaxf((float)c, 1.0f);
    shas[tid] = c;
  }
  __syncthreads();
  for (int idx = tid; idx < 32*Dd; idx += 512){
    int sl = idx >> 7, kk = idx & 127;
    int gi = (tile*32 + sl)*Dd + kk;
    float den = sden[sl];
    float val;
    if (ch == 0)      val = s1[gi]/den;
    else if (ch == 1) val = shas[sl] ? decf(mxb[gi]) : 0.f;
    else if (ch == 2) val = shas[sl] ? decf(mnb[gi]) : 0.f;
    else {
      float mv = s1[gi]/den;
      float var = s2[gi]/den - mv*mv;
      val = sqrtf(fmaxf(var, 0.f) + EPSV);
    }
    lb[sl*136 + kk] = val;
  }
  int cg = tid & 31, rg = tid >> 5;        // 32 col-groups x 16 row-groups (2 rows)
  int c0 = cg*4;
  float a0[2][4], a1[2][4], a2[2][4];
  #pragma unroll
  for (int i = 0; i < 2; i++)
    #pragma unroll
    for (int j = 0; j < 4; j++){ a0[i][j]=0.f; a1[i][j]=0.f; a2[i][j]=0.f; }
  for (int chunk = 0; chunk < 8; ++chunk){
    #pragma unroll
    for (int i = 0; i < 3; ++i){
      int f = tid + i*512;                 // 1536 float4
      int q = f >> 9, r = f & 511;
      int kk = r >> 5, c4 = r & 31;
      int grow = q*512 + ch*128 + chunk*16 + kk;
      ((float4*)wbuf)[f] = *(const float4*)(postW + (size_t)grow*Dd + c4*4);
    }
    __syncthreads();
    #pragma unroll
    for (int k4 = 0; k4 < 4; ++k4){
      float4 av0 = *(const float4*)&lb[(rg*2+0)*136 + chunk*16 + k4*4];
      float4 av1 = *(const float4*)&lb[(rg*2+1)*136 + chunk*16 + k4*4];
      #pragma unroll
      for (int j = 0; j < 4; ++j){
        int kk = k4*4 + j;
        float4 w0 = *(const float4*)&wbuf[kk*128 + c0];
        float4 w1 = *(const float4*)&wbuf[(16+kk)*128 + c0];
        float4 w2 = *(const float4*)&wbuf[(32+kk)*128 + c0];
        float av[2] = { (&av0.x)[j], (&av1.x)[j] };
        #pragma unroll
        for (int i = 0; i < 2; i++){
          float a = av[i];
          a0[i][0] += a*w0.x; a0[i][1] += a*w0.y; a0[i][2] += a*w0.z; a0[i][3] += a*w0.w;
          a1[i][0] += a*w1.x; a1[i][1] += a*w1.y; a1[i][2] += a*w1.z; a1[i][3] += a*w1.w;
          a2[i][0] += a*w2.x; a2[i][1] += a*w2.y; a2[i][2] += a*w2.z; a2[i][3] += a*w2.w;
        }
      }
    }
    __syncthreads();
  }
  #pragma unroll
  for (int i = 0; i < 2; i++){
    int slot = tile*32 + rg*2 + i;
    if (slot < na){
      float dg = slot_deg[slot];
      float logd = logf(dg + 1.f);
      float al = logd/avg, be = avg/logd;
      float4 r;
      r.x = a0[i][0] + al*a1[i][0] + be*a2[i][0];
      r.y = a0[i][1] + al*a1[i][1] + be*a2[i][1];
      r.z = a0[i][2] + al*a1[i][2] + be*a2[i][2];
      r.w = a0[i][3] + al*a1[i][3] + be*a2[i][3];
      *(float4*)(tpart + (size_t)ch*MAXACT*Dd + (size_t)slot*Dd + c0) = r;
    }
  }
}

// ---------------- k_out_resid: out GEMM + residual ----------------
__global__ __launch_bounds__(256) void k_out_resid(
    const float* __restrict__ tpart, const int* __restrict__ alist,
    const float* __restrict__ outW, const float* __restrict__ outb,
    const float* __restrict__ postb, float* __restrict__ hidden,
    const unsigned* __restrict__ ctr){
  int na = (int)ctr[0];
  int tile = blockIdx.x;
  if (tile*32 >= na) return;
  __shared__ float tr[32*136];
  __shared__ float wbuf[16*128];
  int tid = threadIdx.x;
  for (int idx = tid; idx < 32*Dd; idx += 256){
    int sl = idx >> 7, kk = idx & 127;
    size_t o = (size_t)(tile*32 + sl)*Dd + kk;
    tr[sl*136 + kk] = tpart[o] + tpart[(size_t)MAXACT*Dd + o]
                    + tpart[(size_t)2*MAXACT*Dd + o] + tpart[(size_t)3*MAXACT*Dd + o]
                    + postb[kk];
  }
  int cg = tid & 31, rg = tid >> 5;        // 32 col-groups x 8 row-groups (4 rows)
  int c0 = cg*4;
  float4 ob = *(const float4*)(outb + c0);
  float acc[4][4];
  #pragma unroll
  for (int r = 0; r < 4; r++){ acc[r][0]=ob.x; acc[r][1]=ob.y; acc[r][2]=ob.z; acc[r][3]=ob.w; }
  for (int chunk = 0; chunk < 8; ++chunk){
    #pragma unroll
    for (int i = 0; i < 2; ++i){
      int f = tid + i*256;                 // 512 float4
      int kk = f >> 5, c4 = f & 31;
      ((float4*)wbuf)[f] = *(const float4*)(outW + (size_t)(chunk*16 + kk)*Dd + c4*4);
    }
    __syncthreads();
    #pragma unroll
    for (int k4 = 0; k4 < 4; ++k4){
      float4 av[4];
      #pragma unroll
      for (int r = 0; r < 4; r++)
        av[r] = *(const float4*)&tr[(rg*4+r)*136 + chunk*16 + k4*4];
      #pragma unroll
      for (int j = 0; j < 4; ++j){
        float4 w = *(const float4*)&wbuf[(k4*4+j)*128 + c0];
        #pragma unroll
        for (int r = 0; r < 4; r++){
          float a = (&av[r].x)[j];
          acc[r][0] += a*w.x; acc[r][1] += a*w.y; acc[r][2] += a*w.z; acc[r][3] += a*w.w;
        }
      }
    }
    __syncthreads();
  }
  #pragma unroll
  for (int r = 0; r < 4; r++){
    int slot = tile*32 + rg*4 + r;
    if (slot < na){
      int v = alist[slot];
      float* hp = hidden + (size_t)v*Dd + c0;
      float4 h4 = *(float4*)hp;
      h4.x += acc[r][0]; h4.y += acc[r][1]; h4.z += acc[r][2]; h4.w += acc[r][3];
      *(float4*)hp = h4;
    }
  }
}

// ---------------- k_score: score rows from a list; ovr path writes d_out directly ----------------
__global__ __launch_bounds__(256) void k_score(
    const float* __restrict__ hidden, const float* __restrict__ cvec,
    const float* __restrict__ linW,
    const float* __restrict__ m1W, const float* __restrict__ m1b,
    const float* __restrict__ m2W, const float* __restrict__ m2b,
    const int* __restrict__ tlist, const unsigned* __restrict__ ctr,
    float* __restrict__ score,
    const int* __restrict__ ovr, int ovr_n, float* __restrict__ outp){
  int nt = (ovr_n > 0) ? ovr_n : (int)ctr[3];
  const int* list = (ovr_n > 0) ? ovr : tlist;
  int nb = blockIdx.x * 32;
  if (nb >= nt) return;
  __shared__ float sh[32*Dd];
  __shared__ float sx[32*Dd];
  __shared__ float sc[2*Dd];
  __shared__ int   sv[32];
  __shared__ float red[32*33];
  int tid = threadIdx.x;
  if (tid < 32){
    int idx = nb + tid;
    sv[tid] = (idx < nt) ? list[idx] : list[nb];
  }
  sc[tid] = cvec[tid];
  __syncthreads();
  for (int q = tid; q < 32*32; q += 256){
    int row = q >> 5, f4 = q & 31;
    ((float4*)sh)[row*32 + f4] = ((const float4*)(hidden + (size_t)sv[row]*Dd))[f4];
  }
  __syncthreads();
  int cg = tid & 31, rg = tid >> 5;
  int c0 = cg*4;
  float acc[4][4];
  #pragma unroll
  for (int i = 0; i < 4; i++){ acc[i][0]=0.f; acc[i][1]=0.f; acc[i][2]=0.f; acc[i][3]=0.f; }
  for (int k4 = 0; k4 < 32; k4++){
    float4 av[4];
    #pragma unroll
    for (int i = 0; i < 4; i++) av[i] = ((float4*)sh)[(rg*4+i)*32 + k4];
    #pragma unroll
    for (int j = 0; j < 4; j++){
      float4 w = *(const float4*)(linW + (size_t)(k4*4+j)*Dd + c0);
      #pragma unroll
      for (int i = 0; i < 4; i++){
        float a = (&av[i].x)[j];
        acc[i][0] += a*w.x; acc[i][1] += a*w.y; acc[i][2] += a*w.z; acc[i][3] += a*w.w;
      }
    }
  }
  #pragma unroll
  for (int i = 0; i < 4; i++){
    int row = rg*4 + i;
    int bb = (sv[row] >= Nn) ? 1 : 0;
    float4 cv = *(float4*)&sc[bb*Dd + c0];
    float4 hv = ((float4*)sh)[row*32 + cg];
    float4 x;
    x.x = (acc[i][0] + cv.x)*hv.x;
    x.y = (acc[i][1] + cv.y)*hv.y;
    x.z = (acc[i][2] + cv.z)*hv.z;
    x.w = (acc[i][3] + cv.w)*hv.w;
    ((float4*)sx)[row*32 + cg] = x;
  }
  __syncthreads();
  #pragma unroll
  for (int i = 0; i < 4; i++){ acc[i][0]=0.f; acc[i][1]=0.f; acc[i][2]=0.f; acc[i][3]=0.f; }
  for (int k4 = 0; k4 < 32; k4++){
    float4 av[4];
    #pragma unroll
    for (int i = 0; i < 4; i++) av[i] = ((float4*)sx)[(rg*4+i)*32 + k4];
    #pragma unroll
    for (int j = 0; j < 4; j++){
      float4 w = *(const float4*)(m1W + (size_t)(k4*4+j)*Dd + c0);
      #pragma unroll
      for (int i = 0; i < 4; i++){
        float a = (&av[i].x)[j];
        acc[i][0] += a*w.x; acc[i][1] += a*w.y; acc[i][2] += a*w.z; acc[i][3] += a*w.w;
      }
    }
  }
  float4 mb = *(const float4*)(m1b + c0);
  float4 mw = *(const float4*)(m2W + c0);
  #pragma unroll
  for (int i = 0; i < 4; i++){
    float p0 = fmaxf(acc[i][0]+mb.x, 0.f)*mw.x;
    float p1 = fmaxf(acc[i][1]+mb.y, 0.f)*mw.y;
    float p2 = fmaxf(acc[i][2]+mb.z, 0.f)*mw.z;
    float p3 = fmaxf(acc[i][3]+mb.w, 0.f)*mw.w;
    red[(rg*4+i)*33 + cg] = p0+p1+p2+p3;
  }
  __syncthreads();
  if (tid < 32){
    float s = m2b[0];
    for (int g = 0; g < 32; g++) s += red[tid*33 + g];
    if (nb + tid < nt){
      if (ovr_n > 0) outp[nb + tid] = s;
      else           score[sv[tid]] = s;
    }
  }
}

// ---------------- launch ----------------
extern "C" void kernel_launch(void* const* d_in, const int* in_sizes, int n_in,
                              void* d_out, int out_size, void* d_ws, size_t ws_size,
                              hipStream_t stream){
  const int*   h_index       = (const int*)d_in[0];
  const int*   r_index       = (const int*)d_in[1];
  const int*   t_index       = (const int*)d_in[2];
  const float* hidden_states = (const float*)d_in[3];
  const int*   edge_index    = (const int*)d_in[4];
  const float* rel_embedding = (const float*)d_in[5];
  const float* lin_W  = (const float*)d_in[6];
  const float* lin_b  = (const float*)d_in[7];
  const float* m1_W   = (const float*)d_in[8];
  const float* m1_b   = (const float*)d_in[9];
  const float* m2_W   = (const float*)d_in[10];
  const float* m2_b   = (const float*)d_in[11];
  const float* pre_W  = (const float*)d_in[12];
  const float* pre_b  = (const float*)d_in[13];
  const float* post_W = (const float*)d_in[14];
  const float* post_b = (const float*)d_in[15];
  const float* out_W  = (const float*)d_in[16];
  const float* out_b  = (const float*)d_in[17];

  char* ws = (char*)d_ws;
  float*    hidden   = (float*)(ws + HID_OFF);
  float*    score    = (float*)(ws + SCORE_OFF);
  float*    cvec     = (float*)(ws + CVEC_OFF);
  int*      hdr      = (int*)(ws + HDR_OFF);
  unsigned long long* thr = (unsigned long long*)(ws + THR_OFF);
  unsigned* incnt    = (unsigned*)(ws + INC_OFF);
  unsigned* deg0     = (unsigned*)(ws + DEG_OFF);
  int*      node_slot= (int*)(ws + SLOT_OFF);
  float*    slot_deg = (float*)(ws + SDEG_OFF);
  float*    s1       = (float*)(ws + S1_OFF);
  float*    s2       = (float*)(ws + S2_OFF);
  unsigned* mxb      = (unsigned*)(ws + MXB_OFF);
  unsigned* mnb      = (unsigned*)(ws + MNB_OFF);
  float*    tpart    = (float*)(ws + TPART_OFF);
  int*      alist    = (int*)(ws + ALIST_OFF);
  unsigned* flag     = (unsigned*)(ws + FLAG_OFF);
  int*      tlist    = (int*)(ws + TLIST_OFF);
  int*      edges    = (int*)(ws + EDGE_OFF);
  unsigned* ctr      = (unsigned*)(ws + CTR_OFF);

  k_init<<<416, 256, 0, stream>>>(h_index, r_index, t_index, hidden_states, rel_embedding,
                                  lin_W, lin_b, m1_W, m1_b, m2_W, m2_b,
                                  hdr, cvec, hidden, score, flag, tlist, deg0, ctr);
  for (int l = 0; l < Ll; ++l){
    const float* preWl  = pre_W  + (size_t)l*2*Dd*Dd;
    const float* prebl  = pre_b  + (size_t)l*Dd;
    const float* postWl = post_W + (size_t)l*12*Dd*Dd;
    const float* postbl = post_b + (size_t)l*Dd;
    const float* outWl  = out_W  + (size_t)l*Dd*Dd;
    const float* outbl  = out_b  + (size_t)l*Dd;

    k_selzero<<<130, 256, 0, stream>>>(score, tlist, thr, s1, s2, mxb, mnb,
                                       incnt, ctr, edge_index, deg0, (l == 0) ? 1 : 0);
    k_build<<<(Ee + 255)/256, 256, 0, stream>>>(edge_index, score, thr, deg0,
                                                node_slot, alist, slot_deg, incnt,
                                                edges, ctr, flag, tlist);
    k_messages<<<384, 256, 0, stream>>>(hidden, edges, node_slot, preWl, prebl,
                                        s1, s2, mxb, mnb, ctr);
    k_post<<<256, 512, 0, stream>>>(incnt, alist, s1, s2, mxb, mnb, slot_deg,
                                    postWl, tpart, ctr);
    k_out_resid<<<MAXACT/32, 256, 0, stream>>>(tpart, alist, outWl, outbl, postbl,
                                               hidden, ctr);
    if (l < Ll-1){
      k_score<<<MAXTOUCH/32, 256, 0, stream>>>(hidden, cvec, lin_W, m1_W, m1_b, m2_W, m2_b,
                                               tlist, ctr, score, tlist, 0, score);
    } else {
      k_score<<<1, 256, 0, stream>>>(hidden, cvec, lin_W, m1_W, m1_b, m2_W, m2_b,
                                     tlist, ctr, score, hdr + 4, Bq*NEG, (float*)d_out);
    }
  }
}